// Round 19
// baseline (969.688 us; speedup 1.0000x reference)
//
#include <hip/hip_runtime.h>
#include <cstdint>
#include <cstddef>

#define NN 16384
#define IND 1024
#define HD 256
#define KNN 5
#define NCAND 16   // per j-half
#define NC2 32     // total candidates per row (2 halves)

typedef __attribute__((ext_vector_type(4))) float f32x4;
typedef __attribute__((ext_vector_type(8))) short bf16x8;

// ===================== fp32 -> bf16 helpers =====================
__device__ __forceinline__ ushort f2bf(float f) {
  uint32_t u = __float_as_uint(f);
  uint32_t r = (u + 0x7fffu + ((u >> 16) & 1u)) >> 16;
  return (ushort)r;
}
__device__ __forceinline__ float bf2f(ushort s) {
  return __uint_as_float(((uint32_t)s) << 16);
}

// ===================== MFMA GEMM via split-bf16 3-term (r17-measured) =====================
// C[M][N] = op(A@B [+bias] [*rowscale[m]]); A: MxK f32 row-major, B: KxN f32 row-major.
template<bool RELU, bool BIAS, bool RS>
__global__ __launch_bounds__(256) void gemm_mfma(
    const float* __restrict__ A, const float* __restrict__ B,
    const float* __restrict__ bias, const float* __restrict__ rowscale,
    float* __restrict__ C, int M, int N, int K)
{
  __shared__ ushort Ahi[128 * 40], Alo[128 * 40];   // [m][k], row 40 us (80B, padded)
  __shared__ ushort Bhi[128 * 40], Blo[128 * 40];   // [n][k] transposed
  const int tid  = threadIdx.x;
  const int wave = tid >> 6, lane = tid & 63;
  const int l15  = lane & 15, kgrp = lane >> 4;
  const int m0 = blockIdx.x * 128, n0 = blockIdx.y * 128;

  f32x4 acc[8][2];
  #pragma unroll
  for (int fi = 0; fi < 8; ++fi)
    #pragma unroll
    for (int fj = 0; fj < 2; ++fj) acc[fi][fj] = (f32x4){0.f, 0.f, 0.f, 0.f};

  const int arow = tid >> 1, ahalf = tid & 1;       // A: 2 thr/row, 16 k each
  const int bn = tid >> 1, bkh = tid & 1;           // B: 2 thr/n-col, 16 k each

  for (int kb = 0; kb < K; kb += 32) {
    #pragma unroll
    for (int c = 0; c < 4; ++c) {
      float4 v = *(const float4*)&A[(size_t)(m0 + arow) * K + kb + ahalf * 16 + c * 4];
      int o = arow * 40 + ahalf * 16 + c * 4;
      ushort h0 = f2bf(v.x), h1 = f2bf(v.y), h2 = f2bf(v.z), h3 = f2bf(v.w);
      ushort4 H; H.x = h0; H.y = h1; H.z = h2; H.w = h3;
      ushort4 L; L.x = f2bf(v.x - bf2f(h0)); L.y = f2bf(v.y - bf2f(h1));
      L.z = f2bf(v.z - bf2f(h2)); L.w = f2bf(v.w - bf2f(h3));
      *(ushort4*)&Ahi[o] = H;
      *(ushort4*)&Alo[o] = L;
    }
    #pragma unroll
    for (int i = 0; i < 16; ++i) {
      int k = bkh * 16 + i;
      float v = B[(size_t)(kb + k) * N + n0 + bn];
      ushort h = f2bf(v);
      Bhi[bn * 40 + k] = h;
      Blo[bn * 40 + k] = f2bf(v - bf2f(h));
    }
    __syncthreads();

    bf16x8 aH[2], aL[2];
    #pragma unroll
    for (int fj = 0; fj < 2; ++fj) {
      const int mr = wave * 32 + fj * 16 + l15;
      aH[fj] = *(const bf16x8*)&Ahi[mr * 40 + kgrp * 8];
      aL[fj] = *(const bf16x8*)&Alo[mr * 40 + kgrp * 8];
    }
    #pragma unroll
    for (int fi = 0; fi < 8; ++fi) {
      const int nr = fi * 16 + l15;
      bf16x8 bH = *(const bf16x8*)&Bhi[nr * 40 + kgrp * 8];
      bf16x8 bL = *(const bf16x8*)&Blo[nr * 40 + kgrp * 8];
      #pragma unroll
      for (int fj = 0; fj < 2; ++fj) {
        acc[fi][fj] = __builtin_amdgcn_mfma_f32_16x16x32_bf16(aH[fj], bH, acc[fi][fj], 0, 0, 0);
        acc[fi][fj] = __builtin_amdgcn_mfma_f32_16x16x32_bf16(aH[fj], bL, acc[fi][fj], 0, 0, 0);
        acc[fi][fj] = __builtin_amdgcn_mfma_f32_16x16x32_bf16(aL[fj], bH, acc[fi][fj], 0, 0, 0);
      }
    }
    __syncthreads();
  }

  float bv[8];
  if (BIAS) {
    #pragma unroll
    for (int fi = 0; fi < 8; ++fi) bv[fi] = bias[n0 + fi * 16 + l15];
  }
  float rsv[2][4];
  if (RS) {
    #pragma unroll
    for (int fj = 0; fj < 2; ++fj)
      #pragma unroll
      for (int r = 0; r < 4; ++r)
        rsv[fj][r] = rowscale[m0 + wave * 32 + fj * 16 + kgrp * 4 + r];
  }
  #pragma unroll
  for (int fi = 0; fi < 8; ++fi) {
    const int n = n0 + fi * 16 + l15;
    #pragma unroll
    for (int fj = 0; fj < 2; ++fj) {
      #pragma unroll
      for (int r = 0; r < 4; ++r) {
        const int m = m0 + wave * 32 + fj * 16 + kgrp * 4 + r;
        float v = acc[fi][fj][r];
        if (BIAS) v += bv[fi];
        if (RS) v *= rsv[fj][r];
        if (RELU) v = fmaxf(v, 0.0f);
        C[(size_t)m * N + n] = v;
      }
    }
  }
}

// ===================== fused row-norms + bf16 cast (one pass over h) ==========
__global__ __launch_bounds__(256) void sq_split_kernel(
    const float* __restrict__ h, float* __restrict__ sq, ushort* __restrict__ hhi)
{
  const int w = threadIdx.x >> 6, l = threadIdx.x & 63;
  const int r = blockIdx.x * 4 + w;
  float4 v = *(const float4*)&h[(size_t)r * HD + l * 4];
  float s = v.x * v.x + v.y * v.y + v.z * v.z + v.w * v.w;
  #pragma unroll
  for (int o = 32; o; o >>= 1) s += __shfl_down(s, o);
  if (l == 0) sq[r] = s;
  ushort4 H; H.x = f2bf(v.x); H.y = f2bf(v.y); H.z = f2bf(v.z); H.w = f2bf(v.w);
  *(ushort4*)&hhi[(size_t)r * HD + l * 4] = H;
}

// sorted u32-key top-5 insert (k0<k1<...<k4); key embeds index -> unique; equal
// distance-bits -> lower index = lower key (matches JAX tie-break pre-rescore).
#define INS5K(v, k) do {                                                \
    if ((k) < v[4]) {                                                   \
      if ((k) < v[0])      { v[4]=v[3];v[3]=v[2];v[2]=v[1];v[1]=v[0];v[0]=(k); } \
      else if ((k) < v[1]) { v[4]=v[3];v[3]=v[2];v[2]=v[1];v[1]=(k); }  \
      else if ((k) < v[2]) { v[4]=v[3];v[3]=v[2];v[2]=(k); }            \
      else if ((k) < v[3]) { v[4]=v[3];v[3]=(k); }                      \
      else                 { v[4]=(k); }                                \
    }                                                                   \
  } while (0)

// ===================== MFMA pairwise-distance -> top-16 candidates per j-half ==========
// r18-measured structure (367us): r6 geometry (128-row panel, grid (128,2), 512 thr,
// barrier-free K-loop, phase-locked co-resident grid) + 1-term bf16 Gram + u32 keys.
// NEW: float-threshold FAST-PATH in the epilogue. thr[fi] = conservative unpack of
// keys[fi][4] (index bits forced to 1s -> thr >= true 5th-best d), so any candidate
// with key < keys[4] satisfies d <= thr; the common case (no insert) costs only
// fmaf + cmp. Pack/self-check/ladder run only under the rare hit mask.
// Lane owns i = fi*16+(lane&15); j = wave*32 + fj*16 + (lane>>4)*4 + reg.
__global__ __launch_bounds__(512, 2) void dist_topk_mfma(
    const ushort* __restrict__ hhi, const float* __restrict__ sq, int* __restrict__ cand)
{
  // iHi [128][264 us] = 67584 B; merge M (uint, aliases @0): 128 x 40 x 4B = 20480 B.
  __shared__ char smem[67584];
  ushort*   iHi = (ushort*)smem;
  uint32_t* M   = (uint32_t*)smem;

  const int tid  = threadIdx.x;
  const int wave = tid >> 6, lane = tid & 63;
  const int l15  = lane & 15, kgrp = lane >> 4;
  const int rbase = blockIdx.x * 128;
  const int jbeg  = blockIdx.y * (NN / 2);

  // ---- stage i-panel (128 x 256 bf16), once: 4 threads/row, 64 us (8 x uint4) each
  {
    const int r = tid >> 2, q = tid & 3;
    const uint4* sH = (const uint4*)&hhi[(size_t)(rbase + r) * HD + q * 64];
    uint4* dH = (uint4*)&iHi[r * 264 + q * 64];
    #pragma unroll
    for (int c = 0; c < 8; ++c) dH[c] = sH[c];
  }
  __syncthreads();

  uint32_t keys[8][5];
  float thr[8];
  #pragma unroll
  for (int i = 0; i < 8; ++i) {
    thr[i] = 3.0e38f;
    #pragma unroll
    for (int s = 0; s < 5; ++s) keys[i][s] = 0xFFFFFFFFu;
  }

  for (int j0 = jbeg; j0 < jbeg + NN / 2; j0 += 256) {
    f32x4 acc[8][2];
    #pragma unroll
    for (int fi = 0; fi < 8; ++fi) {
      acc[fi][0] = (f32x4){0.f, 0.f, 0.f, 0.f};
      acc[fi][1] = (f32x4){0.f, 0.f, 0.f, 0.f};
    }

    #pragma unroll 2
    for (int kb = 0; kb < 8; ++kb) {
      bf16x8 a0 = *(const bf16x8*)&hhi[(size_t)(j0 + wave * 32 + l15) * HD + kb * 32 + kgrp * 8];
      bf16x8 a1 = *(const bf16x8*)&hhi[(size_t)(j0 + wave * 32 + 16 + l15) * HD + kb * 32 + kgrp * 8];
      #pragma unroll
      for (int fi = 0; fi < 8; ++fi) {
        bf16x8 b = *(const bf16x8*)&iHi[(fi * 16 + l15) * 264 + kb * 32 + kgrp * 8];
        acc[fi][0] = __builtin_amdgcn_mfma_f32_16x16x32_bf16(a0, b, acc[fi][0], 0, 0, 0);
        acc[fi][1] = __builtin_amdgcn_mfma_f32_16x16x32_bf16(a1, b, acc[fi][1], 0, 0, 0);
      }
    }

    float4 sqa = *(const float4*)&sq[j0 + wave * 32 + kgrp * 4];
    float4 sqb = *(const float4*)&sq[j0 + wave * 32 + 16 + kgrp * 4];
    float sqv[2][4] = { { sqa.x, sqa.y, sqa.z, sqa.w }, { sqb.x, sqb.y, sqb.z, sqb.w } };

    #pragma unroll
    for (int fi = 0; fi < 8; ++fi) {
      const int ig = rbase + fi * 16 + l15;
      #pragma unroll
      for (int fj = 0; fj < 2; ++fj) {
        #pragma unroll
        for (int r = 0; r < 4; ++r) {
          float d = fmaf(-2.0f, acc[fi][fj][r], sqv[fj][r]);
          if (d <= thr[fi]) {                               // rare hit path
            const int jg = j0 + wave * 32 + fj * 16 + kgrp * 4 + r;
            if (jg != ig) {
              uint32_t u = __float_as_uint(d);
              u ^= (uint32_t)((int32_t)u >> 31) | 0x80000000u;
              uint32_t key = (u & 0xFFFFC000u) | (uint32_t)jg;
              INS5K(keys[fi], key);
              uint32_t k4 = keys[fi][4];
              if (k4 != 0xFFFFFFFFu) {
                uint32_t uu = k4 | 0x3FFFu;                 // index bits -> 1s (conservative)
                thr[fi] = (uu & 0x80000000u) ? __uint_as_float(uu ^ 0x80000000u)
                                             : __uint_as_float(~uu);
              }
            }
          }
        }
      }
    }
  }

  // ---- merge 4 kgrp partials within each wave (shuffle butterfly, lane bits 4,5)
  #pragma unroll
  for (int fi = 0; fi < 8; ++fi) {
    #pragma unroll
    for (int m = 16; m <= 32; m <<= 1) {
      uint32_t ok[5];
      #pragma unroll
      for (int s = 0; s < 5; ++s)
        ok[s] = (uint32_t)__shfl_xor((int)keys[fi][s], m);
      #pragma unroll
      for (int s = 0; s < 5; ++s) INS5K(keys[fi], ok[s]);
    }
  }

  // ---- 8 wave-partials x 5 keys per row -> LDS -> top-16 candidates for this half
  __syncthreads();   // i-panel reads done; reuse LDS as M
  if (kgrp == 0) {
    #pragma unroll
    for (int fi = 0; fi < 8; ++fi) {
      const int row = fi * 16 + l15;
      #pragma unroll
      for (int s = 0; s < 5; ++s)
        M[row * 40 + wave * 5 + s] = keys[fi][s];
    }
  }
  __syncthreads();
  if (tid < 128) {
    const int irow = rbase + tid;
    int* co = &cand[(size_t)irow * NC2 + blockIdx.y * NCAND];
    #pragma unroll 1
    for (int s = 0; s < NCAND; ++s) {
      uint32_t best = 0xFFFFFFFFu; int bestt = 0;
      #pragma unroll 1
      for (int t = 0; t < 40; ++t) {
        uint32_t v = M[tid * 40 + t];
        if (v < best) { best = v; bestt = t; }
      }
      M[tid * 40 + bestt] = 0xFFFFFFFFu;
      co[s] = (int)(best & 0x3FFFu);
    }
  }
}

// ===================== exact fp32 rescore of 32 candidates -> top-5 =====================
__global__ __launch_bounds__(128) void rescore_kernel(
    const float* __restrict__ h, const float* __restrict__ sq,
    const int* __restrict__ cand, int* __restrict__ nbr)
{
  __shared__ float hi_s[HD];
  __shared__ float dv[NC2];
  __shared__ int   di[NC2];
  const int i = blockIdx.x;
  const int t = threadIdx.x;
  if (t < 64) *(float4*)&hi_s[t * 4] = *(const float4*)&h[(size_t)i * HD + t * 4];
  __syncthreads();
  const int c = t >> 2, q = t & 3;
  const int j = cand[(size_t)i * NC2 + c];
  float s = 0.f;
  const float4* hj  = (const float4*)&h[(size_t)j * HD + q * 64];
  const float4* hi4 = (const float4*)&hi_s[q * 64];
  #pragma unroll
  for (int u = 0; u < 16; ++u) {
    float4 a = hi4[u], b = hj[u];
    s = fmaf(a.x, b.x, s); s = fmaf(a.y, b.y, s);
    s = fmaf(a.z, b.z, s); s = fmaf(a.w, b.w, s);
  }
  s += __shfl_down(s, 1);
  s += __shfl_down(s, 2);
  if (q == 0) { dv[c] = fmaf(-2.0f, s, sq[j]); di[c] = j; }
  __syncthreads();
  if (t == 0) {
    #pragma unroll 1
    for (int sidx = 0; sidx < KNN; ++sidx) {
      float bestv = 3.0e38f; int bestid = 0x7fffffff; int bestc = 0;
      #pragma unroll 1
      for (int u = 0; u < NC2; ++u) {
        float v = dv[u]; int id = di[u];
        if (v < bestv || (v == bestv && id < bestid)) { bestv = v; bestid = id; bestc = u; }
      }
      dv[bestc] = 3.0e38f;
      nbr[i * KNN + sidx] = bestid;
    }
  }
}

// ===================== graph build =====================
__global__ void count_kernel(const int* __restrict__ nbr, int* __restrict__ cnt)
{
  int e = blockIdx.x * 256 + threadIdx.x;
  if (e < NN * KNN) atomicAdd(&cnt[nbr[e]], 1);
}

__global__ void dinv_kernel(const int* __restrict__ cnt, float* __restrict__ dinv)
{
  int i = blockIdx.x * 256 + threadIdx.x;
  if (i < NN) dinv[i] = 1.0f / sqrtf((float)(cnt[i] + KNN + 1));
}

__global__ __launch_bounds__(256) void scan_kernel(const int* __restrict__ cnt, int* __restrict__ off)
{
  __shared__ int ps[256];
  const int t = threadIdx.x;
  int s = 0;
  for (int i = 0; i < 64; ++i) s += cnt[t * 64 + i];
  ps[t] = s;
  __syncthreads();
  if (t == 0) {
    int run = 0;
    for (int q = 0; q < 256; ++q) { int v = ps[q]; ps[q] = run; run += v; }
  }
  __syncthreads();
  int base = ps[t];
  for (int i = 0; i < 64; ++i) { off[t * 64 + i] = base; base += cnt[t * 64 + i]; }
}

__global__ void fill_rev(const int* __restrict__ nbr, const int* __restrict__ off,
                         int* __restrict__ cur, int* __restrict__ rev)
{
  int e = blockIdx.x * 256 + threadIdx.x;
  if (e < NN * KNN) {
    int i = e / KNN;
    int c = nbr[e];
    int s = atomicAdd(&cur[c], 1);
    rev[off[c] + s] = i;
  }
}

// ===================== GCN aggregation (pure gather via reverse CSR) =====================
__global__ __launch_bounds__(64) void aggregate(
    const float* __restrict__ g, const int* __restrict__ nbr,
    const int* __restrict__ rev, const int* __restrict__ off, const int* __restrict__ cnt,
    const float* __restrict__ dinv, const float* __restrict__ bias,
    float* __restrict__ out, int do_relu)
{
  const int c = blockIdx.x;
  const int l = threadIdx.x;
  const float4* g4 = (const float4*)g;
  float4 v = g4[(size_t)c * (HD / 4) + l];
  float ax = v.x, ay = v.y, az = v.z, aw = v.w;
  #pragma unroll
  for (int k = 0; k < KNN; ++k) {
    int r = nbr[c * KNN + k];
    float4 u = g4[(size_t)r * (HD / 4) + l];
    ax += u.x; ay += u.y; az += u.z; aw += u.w;
  }
  const int o0 = off[c], o1 = o0 + cnt[c];
  for (int j = o0; j < o1; ++j) {
    int r = rev[j];
    float4 u = g4[(size_t)r * (HD / 4) + l];
    ax += u.x; ay += u.y; az += u.z; aw += u.w;
  }
  const float dc = dinv[c];
  float4 b = ((const float4*)bias)[l];
  float rx = ax * dc + b.x, ry = ay * dc + b.y, rz = az * dc + b.z, rw = aw * dc + b.w;
  if (do_relu) {
    rx = fmaxf(rx, 0.0f); ry = fmaxf(ry, 0.0f);
    rz = fmaxf(rz, 0.0f); rw = fmaxf(rw, 0.0f);
  }
  float4 o; o.x = rx; o.y = ry; o.z = rz; o.w = rw;
  ((float4*)out)[(size_t)c * (HD / 4) + l] = o;
}

// ===================== mean-pool + classifier =====================
__global__ __launch_bounds__(256) void colsum_kernel(const float* __restrict__ a, float* __restrict__ colsum)
{
  const int f = threadIdx.x;
  const int r0 = blockIdx.x * 64;
  float s = 0.0f;
  for (int r = 0; r < 64; ++r) s += a[(size_t)(r0 + r) * HD + f];
  atomicAdd(&colsum[f], s);
}

__global__ __launch_bounds__(256) void final_kernel(
    const float* __restrict__ colsum, const float* __restrict__ Wc,
    const float* __restrict__ bc, float* __restrict__ out)
{
  __shared__ float s0[256], s1[256];
  const int f = threadIdx.x;
  float bag = colsum[f] * (1.0f / (float)NN);
  s0[f] = bag * Wc[f * 2 + 0];
  s1[f] = bag * Wc[f * 2 + 1];
  __syncthreads();
  for (int st = 128; st; st >>= 1) {
    if (f < st) { s0[f] += s0[f + st]; s1[f] += s1[f + st]; }
    __syncthreads();
  }
  if (f == 0) { out[0] = s0[0] + bc[0]; out[1] = s1[0] + bc[1]; }
}

// ===================== launch =====================
extern "C" void kernel_launch(void* const* d_in, const int* in_sizes, int n_in,
                              void* d_out, int out_size, void* d_ws, size_t ws_size,
                              hipStream_t stream)
{
  const float* x   = (const float*)d_in[0];
  const float* Wp  = (const float*)d_in[1];
  const float* bp  = (const float*)d_in[2];
  const float* Wg1 = (const float*)d_in[3];
  const float* bg1 = (const float*)d_in[4];
  const float* Wg2 = (const float*)d_in[5];
  const float* bg2 = (const float*)d_in[6];
  const float* Wc  = (const float*)d_in[7];
  const float* bc  = (const float*)d_in[8];
  float* out = (float*)d_out;

  float* ws    = (float*)d_ws;
  float* h     = ws;                                // N*HD f32
  float* g     = ws + (size_t)NN * HD;              // N*HD f32 (written step 8)
  float* h1    = ws + 2 * (size_t)NN * HD;          // N*HD f32 (written step 9)
  float* agg2  = h;                                 // reuse
  float* sq    = ws + 3 * (size_t)NN * HD;          // N
  float* dinv  = sq + NN;                           // N
  float* colsum= dinv + NN;                         // HD
  int* nbr = (int*)(colsum + HD);                   // N*KNN
  int* cnt = nbr + NN * KNN;                        // N
  int* off = cnt + NN;                              // N
  int* cur = off + NN;                              // N
  int* rev = cur + NN;                              // N*KNN
  // bf16 hi lives in g region (dead until step 8, after kNN phase)
  ushort* hhi = (ushort*)g;
  int* cand = (int*)(g + (size_t)NN * HD * 3 / 4);  // N*NC2 ints = 2 MB

  // 1. h = relu(x @ W_proj + b_proj)  [MFMA split-bf16 3-term]
  gemm_mfma<true, true, false><<<dim3(NN / 128, HD / 128), dim3(256), 0, stream>>>(
      x, Wp, bp, nullptr, h, NN, HD, IND);
  // 2. sq + bf16 cast (single pass over h)
  sq_split_kernel<<<dim3(NN / 4), dim3(256), 0, stream>>>(h, sq, hhi);
  // 3a. approx top-16 per j-half (r6 geometry + 1-term Gram + u32 keys + thr fast-path)
  dist_topk_mfma<<<dim3(NN / 128, 2), dim3(512), 0, stream>>>(hhi, sq, cand);
  // 3b. exact fp32 rescore of 32 candidates -> top-5
  rescore_kernel<<<dim3(NN), dim3(128), 0, stream>>>(h, sq, cand, nbr);
  // 4. in-degree counts
  hipMemsetAsync(cnt, 0, NN * sizeof(int), stream);
  count_kernel<<<dim3((NN * KNN) / 256), dim3(256), 0, stream>>>(nbr, cnt);
  // 5. dinv
  dinv_kernel<<<dim3(NN / 256), dim3(256), 0, stream>>>(cnt, dinv);
  // 6. CSR offsets
  scan_kernel<<<dim3(1), dim3(256), 0, stream>>>(cnt, off);
  // 7. reverse adjacency
  hipMemsetAsync(cur, 0, NN * sizeof(int), stream);
  fill_rev<<<dim3((NN * KNN) / 256), dim3(256), 0, stream>>>(nbr, off, cur, rev);
  // 8. g = (h @ W_g1) * dinv[row]  [MFMA]
  gemm_mfma<false, false, true><<<dim3(NN / 128, HD / 128), dim3(256), 0, stream>>>(
      h, Wg1, nullptr, dinv, g, NN, HD, HD);
  // 9. h1 = relu(agg(g) + b_g1)
  aggregate<<<dim3(NN), dim3(64), 0, stream>>>(g, nbr, rev, off, cnt, dinv, bg1, h1, 1);
  // 10. g = (h1 @ W_g2) * dinv[row]  [MFMA]
  gemm_mfma<false, false, true><<<dim3(NN / 128, HD / 128), dim3(256), 0, stream>>>(
      h1, Wg2, nullptr, dinv, g, NN, HD, HD);
  // 11. agg2 = agg(g) + b_g2
  aggregate<<<dim3(NN), dim3(64), 0, stream>>>(g, nbr, rev, off, cnt, dinv, bg2, agg2, 0);
  // 12/13. mean-pool + classifier
  hipMemsetAsync(colsum, 0, HD * sizeof(float), stream);
  colsum_kernel<<<dim3(NN / 64), dim3(256), 0, stream>>>(agg2, colsum);
  final_kernel<<<dim3(1), dim3(256), 0, stream>>>(colsum, Wc, bc, out);
}

// Round 20
// 922.956 us; speedup vs baseline: 1.0506x; 1.0506x over previous
//
#include <hip/hip_runtime.h>
#include <cstdint>
#include <cstddef>

#define NN 16384
#define IND 1024
#define HD 256
#define KNN 5
#define NCAND 16   // per j-half
#define NC2 32     // total candidates per row (2 halves)

typedef __attribute__((ext_vector_type(4))) float f32x4;
typedef __attribute__((ext_vector_type(8))) short bf16x8;

// ===================== fp32 -> bf16 helpers =====================
__device__ __forceinline__ ushort f2bf(float f) {
  uint32_t u = __float_as_uint(f);
  uint32_t r = (u + 0x7fffu + ((u >> 16) & 1u)) >> 16;
  return (ushort)r;
}
__device__ __forceinline__ float bf2f(ushort s) {
  return __uint_as_float(((uint32_t)s) << 16);
}

// ===================== MFMA GEMM via split-bf16 3-term (r17-measured) =====================
// C[M][N] = op(A@B [+bias] [*rowscale[m]]); A: MxK f32 row-major, B: KxN f32 row-major.
template<bool RELU, bool BIAS, bool RS>
__global__ __launch_bounds__(256) void gemm_mfma(
    const float* __restrict__ A, const float* __restrict__ B,
    const float* __restrict__ bias, const float* __restrict__ rowscale,
    float* __restrict__ C, int M, int N, int K)
{
  __shared__ ushort Ahi[128 * 40], Alo[128 * 40];   // [m][k], row 40 us (80B, padded)
  __shared__ ushort Bhi[128 * 40], Blo[128 * 40];   // [n][k] transposed
  const int tid  = threadIdx.x;
  const int wave = tid >> 6, lane = tid & 63;
  const int l15  = lane & 15, kgrp = lane >> 4;
  const int m0 = blockIdx.x * 128, n0 = blockIdx.y * 128;

  f32x4 acc[8][2];
  #pragma unroll
  for (int fi = 0; fi < 8; ++fi)
    #pragma unroll
    for (int fj = 0; fj < 2; ++fj) acc[fi][fj] = (f32x4){0.f, 0.f, 0.f, 0.f};

  const int arow = tid >> 1, ahalf = tid & 1;       // A: 2 thr/row, 16 k each
  const int bn = tid >> 1, bkh = tid & 1;           // B: 2 thr/n-col, 16 k each

  for (int kb = 0; kb < K; kb += 32) {
    #pragma unroll
    for (int c = 0; c < 4; ++c) {
      float4 v = *(const float4*)&A[(size_t)(m0 + arow) * K + kb + ahalf * 16 + c * 4];
      int o = arow * 40 + ahalf * 16 + c * 4;
      ushort h0 = f2bf(v.x), h1 = f2bf(v.y), h2 = f2bf(v.z), h3 = f2bf(v.w);
      ushort4 H; H.x = h0; H.y = h1; H.z = h2; H.w = h3;
      ushort4 L; L.x = f2bf(v.x - bf2f(h0)); L.y = f2bf(v.y - bf2f(h1));
      L.z = f2bf(v.z - bf2f(h2)); L.w = f2bf(v.w - bf2f(h3));
      *(ushort4*)&Ahi[o] = H;
      *(ushort4*)&Alo[o] = L;
    }
    #pragma unroll
    for (int i = 0; i < 16; ++i) {
      int k = bkh * 16 + i;
      float v = B[(size_t)(kb + k) * N + n0 + bn];
      ushort h = f2bf(v);
      Bhi[bn * 40 + k] = h;
      Blo[bn * 40 + k] = f2bf(v - bf2f(h));
    }
    __syncthreads();

    bf16x8 aH[2], aL[2];
    #pragma unroll
    for (int fj = 0; fj < 2; ++fj) {
      const int mr = wave * 32 + fj * 16 + l15;
      aH[fj] = *(const bf16x8*)&Ahi[mr * 40 + kgrp * 8];
      aL[fj] = *(const bf16x8*)&Alo[mr * 40 + kgrp * 8];
    }
    #pragma unroll
    for (int fi = 0; fi < 8; ++fi) {
      const int nr = fi * 16 + l15;
      bf16x8 bH = *(const bf16x8*)&Bhi[nr * 40 + kgrp * 8];
      bf16x8 bL = *(const bf16x8*)&Blo[nr * 40 + kgrp * 8];
      #pragma unroll
      for (int fj = 0; fj < 2; ++fj) {
        acc[fi][fj] = __builtin_amdgcn_mfma_f32_16x16x32_bf16(aH[fj], bH, acc[fi][fj], 0, 0, 0);
        acc[fi][fj] = __builtin_amdgcn_mfma_f32_16x16x32_bf16(aH[fj], bL, acc[fi][fj], 0, 0, 0);
        acc[fi][fj] = __builtin_amdgcn_mfma_f32_16x16x32_bf16(aL[fj], bH, acc[fi][fj], 0, 0, 0);
      }
    }
    __syncthreads();
  }

  float bv[8];
  if (BIAS) {
    #pragma unroll
    for (int fi = 0; fi < 8; ++fi) bv[fi] = bias[n0 + fi * 16 + l15];
  }
  float rsv[2][4];
  if (RS) {
    #pragma unroll
    for (int fj = 0; fj < 2; ++fj)
      #pragma unroll
      for (int r = 0; r < 4; ++r)
        rsv[fj][r] = rowscale[m0 + wave * 32 + fj * 16 + kgrp * 4 + r];
  }
  #pragma unroll
  for (int fi = 0; fi < 8; ++fi) {
    const int n = n0 + fi * 16 + l15;
    #pragma unroll
    for (int fj = 0; fj < 2; ++fj) {
      #pragma unroll
      for (int r = 0; r < 4; ++r) {
        const int m = m0 + wave * 32 + fj * 16 + kgrp * 4 + r;
        float v = acc[fi][fj][r];
        if (BIAS) v += bv[fi];
        if (RS) v *= rsv[fj][r];
        if (RELU) v = fmaxf(v, 0.0f);
        C[(size_t)m * N + n] = v;
      }
    }
  }
}

// ===================== fused row-norms + bf16 cast (one pass over h) ==========
__global__ __launch_bounds__(256) void sq_split_kernel(
    const float* __restrict__ h, float* __restrict__ sq, ushort* __restrict__ hhi)
{
  const int w = threadIdx.x >> 6, l = threadIdx.x & 63;
  const int r = blockIdx.x * 4 + w;
  float4 v = *(const float4*)&h[(size_t)r * HD + l * 4];
  float s = v.x * v.x + v.y * v.y + v.z * v.z + v.w * v.w;
  #pragma unroll
  for (int o = 32; o; o >>= 1) s += __shfl_down(s, o);
  if (l == 0) sq[r] = s;
  ushort4 H; H.x = f2bf(v.x); H.y = f2bf(v.y); H.z = f2bf(v.z); H.w = f2bf(v.w);
  *(ushort4*)&hhi[(size_t)r * HD + l * 4] = H;
}

// sorted u32-key top-5 insert (k0<k1<...<k4); key embeds index -> unique; equal
// distance-bits -> lower index = lower key (matches JAX tie-break pre-rescore).
#define INS5K(v, k) do {                                                \
    if ((k) < v[4]) {                                                   \
      if ((k) < v[0])      { v[4]=v[3];v[3]=v[2];v[2]=v[1];v[1]=v[0];v[0]=(k); } \
      else if ((k) < v[1]) { v[4]=v[3];v[3]=v[2];v[2]=v[1];v[1]=(k); }  \
      else if ((k) < v[2]) { v[4]=v[3];v[3]=v[2];v[2]=(k); }            \
      else if ((k) < v[3]) { v[4]=v[3];v[3]=(k); }                      \
      else                 { v[4]=(k); }                                \
    }                                                                   \
  } while (0)

// ===================== MFMA pairwise-distance -> top-16 candidates per j-half ==========
// EXACT r18-measured kernel (367us, FETCH 35.7MB, WRITE 2KB): r6 geometry (128-row
// panel, grid (128,2), 512 thr, barrier-free K-loop, phase-locked co-resident grid)
// + 1-term bf16 Gram + packed u32 keys, straight-line epilogue (r19's threshold
// fast-path REGRESSED to 447us: rare-insert branch broke cndmask scheduling).
// Lane owns i = fi*16+(lane&15); j = wave*32 + fj*16 + (lane>>4)*4 + reg.
__global__ __launch_bounds__(512, 2) void dist_topk_mfma(
    const ushort* __restrict__ hhi, const float* __restrict__ sq, int* __restrict__ cand)
{
  // iHi [128][264 us] = 67584 B; merge M (uint, aliases @0): 128 x 40 x 4B = 20480 B.
  __shared__ char smem[67584];
  ushort*   iHi = (ushort*)smem;
  uint32_t* M   = (uint32_t*)smem;

  const int tid  = threadIdx.x;
  const int wave = tid >> 6, lane = tid & 63;
  const int l15  = lane & 15, kgrp = lane >> 4;
  const int rbase = blockIdx.x * 128;
  const int jbeg  = blockIdx.y * (NN / 2);

  // ---- stage i-panel (128 x 256 bf16), once: 4 threads/row, 64 us (8 x uint4) each
  {
    const int r = tid >> 2, q = tid & 3;
    const uint4* sH = (const uint4*)&hhi[(size_t)(rbase + r) * HD + q * 64];
    uint4* dH = (uint4*)&iHi[r * 264 + q * 64];
    #pragma unroll
    for (int c = 0; c < 8; ++c) dH[c] = sH[c];
  }
  __syncthreads();

  uint32_t keys[8][5];
  #pragma unroll
  for (int i = 0; i < 8; ++i)
    #pragma unroll
    for (int s = 0; s < 5; ++s) keys[i][s] = 0xFFFFFFFFu;

  for (int j0 = jbeg; j0 < jbeg + NN / 2; j0 += 256) {
    f32x4 acc[8][2];
    #pragma unroll
    for (int fi = 0; fi < 8; ++fi) {
      acc[fi][0] = (f32x4){0.f, 0.f, 0.f, 0.f};
      acc[fi][1] = (f32x4){0.f, 0.f, 0.f, 0.f};
    }

    #pragma unroll 2
    for (int kb = 0; kb < 8; ++kb) {
      bf16x8 a0 = *(const bf16x8*)&hhi[(size_t)(j0 + wave * 32 + l15) * HD + kb * 32 + kgrp * 8];
      bf16x8 a1 = *(const bf16x8*)&hhi[(size_t)(j0 + wave * 32 + 16 + l15) * HD + kb * 32 + kgrp * 8];
      #pragma unroll
      for (int fi = 0; fi < 8; ++fi) {
        bf16x8 b = *(const bf16x8*)&iHi[(fi * 16 + l15) * 264 + kb * 32 + kgrp * 8];
        acc[fi][0] = __builtin_amdgcn_mfma_f32_16x16x32_bf16(a0, b, acc[fi][0], 0, 0, 0);
        acc[fi][1] = __builtin_amdgcn_mfma_f32_16x16x32_bf16(a1, b, acc[fi][1], 0, 0, 0);
      }
    }

    float4 sqa = *(const float4*)&sq[j0 + wave * 32 + kgrp * 4];
    float4 sqb = *(const float4*)&sq[j0 + wave * 32 + 16 + kgrp * 4];
    float sqv[2][4] = { { sqa.x, sqa.y, sqa.z, sqa.w }, { sqb.x, sqb.y, sqb.z, sqb.w } };

    // self-pair only possible in the one 256-chunk containing this block's 128 i-rows
    const bool selfchunk = ((rbase >> 8) == (j0 >> 8));

#define EPI_SLOT(fi, fj, r, CHECK)                                              \
    {                                                                           \
      const int jg = j0 + wave * 32 + (fj) * 16 + kgrp * 4 + (r);               \
      float d = fmaf(-2.0f, acc[fi][fj][r], sqv[fj][r]);                        \
      uint32_t u = __float_as_uint(d);                                          \
      u ^= (uint32_t)((int32_t)u >> 31) | 0x80000000u;                          \
      uint32_t key = (u & 0xFFFFC000u) | (uint32_t)jg;                          \
      if (!(CHECK) || jg != (rbase + (fi) * 16 + l15)) INS5K(keys[fi], key);    \
    }

    if (selfchunk) {
      #pragma unroll
      for (int fi = 0; fi < 8; ++fi)
        #pragma unroll
        for (int fj = 0; fj < 2; ++fj)
          #pragma unroll
          for (int r = 0; r < 4; ++r) EPI_SLOT(fi, fj, r, true)
    } else {
      #pragma unroll
      for (int fi = 0; fi < 8; ++fi)
        #pragma unroll
        for (int fj = 0; fj < 2; ++fj)
          #pragma unroll
          for (int r = 0; r < 4; ++r) EPI_SLOT(fi, fj, r, false)
    }
#undef EPI_SLOT
  }

  // ---- merge 4 kgrp partials within each wave (shuffle butterfly, lane bits 4,5)
  #pragma unroll
  for (int fi = 0; fi < 8; ++fi) {
    #pragma unroll
    for (int m = 16; m <= 32; m <<= 1) {
      uint32_t ok[5];
      #pragma unroll
      for (int s = 0; s < 5; ++s)
        ok[s] = (uint32_t)__shfl_xor((int)keys[fi][s], m);
      #pragma unroll
      for (int s = 0; s < 5; ++s) INS5K(keys[fi], ok[s]);
    }
  }

  // ---- 8 wave-partials x 5 keys per row -> LDS -> top-16 candidates for this half
  __syncthreads();   // i-panel reads done; reuse LDS as M
  if (kgrp == 0) {
    #pragma unroll
    for (int fi = 0; fi < 8; ++fi) {
      const int row = fi * 16 + l15;
      #pragma unroll
      for (int s = 0; s < 5; ++s)
        M[row * 40 + wave * 5 + s] = keys[fi][s];
    }
  }
  __syncthreads();
  if (tid < 128) {
    const int irow = rbase + tid;
    int* co = &cand[(size_t)irow * NC2 + blockIdx.y * NCAND];
    #pragma unroll 1
    for (int s = 0; s < NCAND; ++s) {
      uint32_t best = 0xFFFFFFFFu; int bestt = 0;
      #pragma unroll 1
      for (int t = 0; t < 40; ++t) {
        uint32_t v = M[tid * 40 + t];
        if (v < best) { best = v; bestt = t; }
      }
      M[tid * 40 + bestt] = 0xFFFFFFFFu;
      co[s] = (int)(best & 0x3FFFu);
    }
  }
}

// ===================== exact fp32 rescore -> top-5 (+ fused in-degree count) ==========
__global__ __launch_bounds__(128) void rescore_kernel(
    const float* __restrict__ h, const float* __restrict__ sq,
    const int* __restrict__ cand, int* __restrict__ nbr, int* __restrict__ cnt)
{
  __shared__ float hi_s[HD];
  __shared__ float dv[NC2];
  __shared__ int   di[NC2];
  const int i = blockIdx.x;
  const int t = threadIdx.x;
  if (t < 64) *(float4*)&hi_s[t * 4] = *(const float4*)&h[(size_t)i * HD + t * 4];
  __syncthreads();
  const int c = t >> 2, q = t & 3;
  const int j = cand[(size_t)i * NC2 + c];
  float s = 0.f;
  const float4* hj  = (const float4*)&h[(size_t)j * HD + q * 64];
  const float4* hi4 = (const float4*)&hi_s[q * 64];
  #pragma unroll
  for (int u = 0; u < 16; ++u) {
    float4 a = hi4[u], b = hj[u];
    s = fmaf(a.x, b.x, s); s = fmaf(a.y, b.y, s);
    s = fmaf(a.z, b.z, s); s = fmaf(a.w, b.w, s);
  }
  s += __shfl_down(s, 1);
  s += __shfl_down(s, 2);
  if (q == 0) { dv[c] = fmaf(-2.0f, s, sq[j]); di[c] = j; }
  __syncthreads();
  if (t == 0) {
    #pragma unroll 1
    for (int sidx = 0; sidx < KNN; ++sidx) {
      float bestv = 3.0e38f; int bestid = 0x7fffffff; int bestc = 0;
      #pragma unroll 1
      for (int u = 0; u < NC2; ++u) {
        float v = dv[u]; int id = di[u];
        if (v < bestv || (v == bestv && id < bestid)) { bestv = v; bestid = id; bestc = u; }
      }
      dv[bestc] = 3.0e38f;
      nbr[i * KNN + sidx] = bestid;
      atomicAdd(&cnt[bestid], 1);   // fused in-degree count (sum is order-independent)
    }
  }
}

// ===================== graph build =====================
// CSR offsets + dinv in one pass (dinv fused; deg = indeg + K + 1)
__global__ __launch_bounds__(256) void scan_kernel(
    const int* __restrict__ cnt, int* __restrict__ off, float* __restrict__ dinv)
{
  __shared__ int ps[256];
  const int t = threadIdx.x;
  int s = 0;
  for (int i = 0; i < 64; ++i) s += cnt[t * 64 + i];
  ps[t] = s;
  __syncthreads();
  if (t == 0) {
    int run = 0;
    for (int q = 0; q < 256; ++q) { int v = ps[q]; ps[q] = run; run += v; }
  }
  __syncthreads();
  int base = ps[t];
  for (int i = 0; i < 64; ++i) {
    int c = cnt[t * 64 + i];
    off[t * 64 + i] = base;
    dinv[t * 64 + i] = 1.0f / sqrtf((float)(c + KNN + 1));
    base += c;
  }
}

__global__ void fill_rev(const int* __restrict__ nbr, const int* __restrict__ off,
                         int* __restrict__ cur, int* __restrict__ rev)
{
  int e = blockIdx.x * 256 + threadIdx.x;
  if (e < NN * KNN) {
    int i = e / KNN;
    int c = nbr[e];
    int s = atomicAdd(&cur[c], 1);
    rev[off[c] + s] = i;
  }
}

// ===================== GCN aggregation (4 nodes/block, wave per node) ================
__global__ __launch_bounds__(256) void aggregate(
    const float* __restrict__ g, const int* __restrict__ nbr,
    const int* __restrict__ rev, const int* __restrict__ off, const int* __restrict__ cnt,
    const float* __restrict__ dinv, const float* __restrict__ bias,
    float* __restrict__ out, int do_relu)
{
  const int c = blockIdx.x * 4 + (threadIdx.x >> 6);
  const int l = threadIdx.x & 63;
  const float4* g4 = (const float4*)g;
  float4 v = g4[(size_t)c * (HD / 4) + l];
  float ax = v.x, ay = v.y, az = v.z, aw = v.w;
  #pragma unroll
  for (int k = 0; k < KNN; ++k) {
    int r = nbr[c * KNN + k];
    float4 u = g4[(size_t)r * (HD / 4) + l];
    ax += u.x; ay += u.y; az += u.z; aw += u.w;
  }
  const int o0 = off[c], o1 = o0 + cnt[c];
  for (int j = o0; j < o1; ++j) {
    int r = rev[j];
    float4 u = g4[(size_t)r * (HD / 4) + l];
    ax += u.x; ay += u.y; az += u.z; aw += u.w;
  }
  const float dc = dinv[c];
  float4 b = ((const float4*)bias)[l];
  float rx = ax * dc + b.x, ry = ay * dc + b.y, rz = az * dc + b.z, rw = aw * dc + b.w;
  if (do_relu) {
    rx = fmaxf(rx, 0.0f); ry = fmaxf(ry, 0.0f);
    rz = fmaxf(rz, 0.0f); rw = fmaxf(rw, 0.0f);
  }
  float4 o; o.x = rx; o.y = ry; o.z = rz; o.w = rw;
  ((float4*)out)[(size_t)c * (HD / 4) + l] = o;
}

// ===================== mean-pool + classifier =====================
__global__ __launch_bounds__(256) void colsum_kernel(const float* __restrict__ a, float* __restrict__ colsum)
{
  const int f = threadIdx.x;
  const int r0 = blockIdx.x * 64;
  float s = 0.0f;
  for (int r = 0; r < 64; ++r) s += a[(size_t)(r0 + r) * HD + f];
  atomicAdd(&colsum[f], s);
}

__global__ __launch_bounds__(256) void final_kernel(
    const float* __restrict__ colsum, const float* __restrict__ Wc,
    const float* __restrict__ bc, float* __restrict__ out)
{
  __shared__ float s0[256], s1[256];
  const int f = threadIdx.x;
  float bag = colsum[f] * (1.0f / (float)NN);
  s0[f] = bag * Wc[f * 2 + 0];
  s1[f] = bag * Wc[f * 2 + 1];
  __syncthreads();
  for (int st = 128; st; st >>= 1) {
    if (f < st) { s0[f] += s0[f + st]; s1[f] += s1[f + st]; }
    __syncthreads();
  }
  if (f == 0) { out[0] = s0[0] + bc[0]; out[1] = s1[0] + bc[1]; }
}

// ===================== launch =====================
extern "C" void kernel_launch(void* const* d_in, const int* in_sizes, int n_in,
                              void* d_out, int out_size, void* d_ws, size_t ws_size,
                              hipStream_t stream)
{
  const float* x   = (const float*)d_in[0];
  const float* Wp  = (const float*)d_in[1];
  const float* bp  = (const float*)d_in[2];
  const float* Wg1 = (const float*)d_in[3];
  const float* bg1 = (const float*)d_in[4];
  const float* Wg2 = (const float*)d_in[5];
  const float* bg2 = (const float*)d_in[6];
  const float* Wc  = (const float*)d_in[7];
  const float* bc  = (const float*)d_in[8];
  float* out = (float*)d_out;

  float* ws    = (float*)d_ws;
  float* h     = ws;                                // N*HD f32
  float* g     = ws + (size_t)NN * HD;              // N*HD f32 (written step 8)
  float* h1    = ws + 2 * (size_t)NN * HD;          // N*HD f32 (written step 9)
  float* agg2  = h;                                 // reuse
  float* sq    = ws + 3 * (size_t)NN * HD;          // N
  float* dinv  = sq + NN;                           // N
  float* colsum= dinv + NN;                         // HD
  int* nbr = (int*)(colsum + HD);                   // N*KNN
  int* cnt = nbr + NN * KNN;                        // N
  int* off = cnt + NN;                              // N
  int* cur = off + NN;                              // N
  int* rev = cur + NN;                              // N*KNN
  // bf16 hi lives in g region (dead until step 8, after kNN phase)
  ushort* hhi = (ushort*)g;
  int* cand = (int*)(g + (size_t)NN * HD * 3 / 4);  // N*NC2 ints = 2 MB

  // 1. h = relu(x @ W_proj + b_proj)  [MFMA split-bf16 3-term]
  gemm_mfma<true, true, false><<<dim3(NN / 128, HD / 128), dim3(256), 0, stream>>>(
      x, Wp, bp, nullptr, h, NN, HD, IND);
  // 2. sq + bf16 cast (single pass over h)
  sq_split_kernel<<<dim3(NN / 4), dim3(256), 0, stream>>>(h, sq, hhi);
  // 3a. approx top-16 per j-half (r18-measured dist kernel)
  dist_topk_mfma<<<dim3(NN / 128, 2), dim3(512), 0, stream>>>(hhi, sq, cand);
  // 3b. exact fp32 rescore -> top-5, with fused in-degree counts
  hipMemsetAsync(cnt, 0, NN * sizeof(int), stream);
  rescore_kernel<<<dim3(NN), dim3(128), 0, stream>>>(h, sq, cand, nbr, cnt);
  // 4. CSR offsets + dinv (fused)
  scan_kernel<<<dim3(1), dim3(256), 0, stream>>>(cnt, off, dinv);
  // 5. reverse adjacency
  hipMemsetAsync(cur, 0, NN * sizeof(int), stream);
  fill_rev<<<dim3((NN * KNN) / 256), dim3(256), 0, stream>>>(nbr, off, cur, rev);
  // 6. g = (h @ W_g1) * dinv[row]  [MFMA]
  gemm_mfma<false, false, true><<<dim3(NN / 128, HD / 128), dim3(256), 0, stream>>>(
      h, Wg1, nullptr, dinv, g, NN, HD, HD);
  // 7. h1 = relu(agg(g) + b_g1)
  aggregate<<<dim3(NN / 4), dim3(256), 0, stream>>>(g, nbr, rev, off, cnt, dinv, bg1, h1, 1);
  // 8. g = (h1 @ W_g2) * dinv[row]  [MFMA]
  gemm_mfma<false, false, true><<<dim3(NN / 128, HD / 128), dim3(256), 0, stream>>>(
      h1, Wg2, nullptr, dinv, g, NN, HD, HD);
  // 9. agg2 = agg(g) + b_g2
  aggregate<<<dim3(NN / 4), dim3(256), 0, stream>>>(g, nbr, rev, off, cnt, dinv, bg2, agg2, 0);
  // 10/11. mean-pool + classifier
  hipMemsetAsync(colsum, 0, HD * sizeof(float), stream);
  colsum_kernel<<<dim3(NN / 64), dim3(256), 0, stream>>>(agg2, colsum);
  final_kernel<<<dim3(1), dim3(256), 0, stream>>>(colsum, Wc, bc, out);
}

// Round 21
// 900.086 us; speedup vs baseline: 1.0773x; 1.0254x over previous
//
#include <hip/hip_runtime.h>
#include <cstdint>
#include <cstddef>

#define NN 16384
#define IND 1024
#define HD 256
#define KNN 5
#define NCAND 16   // per j-half
#define NC2 32     // total candidates per row (2 halves)

typedef __attribute__((ext_vector_type(4))) float f32x4;
typedef __attribute__((ext_vector_type(8))) short bf16x8;

// ===================== fp32 -> bf16 helpers =====================
__device__ __forceinline__ ushort f2bf(float f) {
  uint32_t u = __float_as_uint(f);
  uint32_t r = (u + 0x7fffu + ((u >> 16) & 1u)) >> 16;
  return (ushort)r;
}
__device__ __forceinline__ float bf2f(ushort s) {
  return __uint_as_float(((uint32_t)s) << 16);
}

// ===================== one-time weight conversion: [K][256] f32 -> [n][K] bf16 hi/lo ====
// Removes the per-block strided scalar B loads + f2bf redone by every GEMM block
// (128x redundant). Runs once per launch; ~1.5MB total output.
__global__ __launch_bounds__(256) void convW_kernel(
    const float* __restrict__ W, ushort* __restrict__ Whi, ushort* __restrict__ Wlo, int K)
{
  int idx = blockIdx.x * 256 + threadIdx.x;   // over K*256
  int k = idx >> 8, n = idx & 255;
  float v = W[idx];
  ushort h = f2bf(v);
  Whi[(size_t)n * K + k] = h;
  Wlo[(size_t)n * K + k] = f2bf(v - bf2f(h));
}

// ===================== MFMA GEMM, split-bf16 3-term, PRE-CONVERTED weights =============
// C[M][N] = op(A@B [+bias] [*rowscale[m]]); A: MxK f32 row-major;
// B given as transposed bf16 hi/lo [n][K]. Tile 128x128, BK=32, 256 thr (4 waves).
// A hi/lo conversion in-kernel (only 2x redundant); B staging = pure uint4 copies.
template<bool RELU, bool BIAS, bool RS>
__global__ __launch_bounds__(256) void gemm_mfma_pw(
    const float* __restrict__ A, const ushort* __restrict__ BhiG,
    const ushort* __restrict__ BloG, const float* __restrict__ bias,
    const float* __restrict__ rowscale, float* __restrict__ C, int M, int N, int K)
{
  __shared__ ushort Ahi[128 * 40], Alo[128 * 40];   // [m][k], row 40 us (80B, padded)
  __shared__ ushort Bhi[128 * 40], Blo[128 * 40];   // [n][k]
  const int tid  = threadIdx.x;
  const int wave = tid >> 6, lane = tid & 63;
  const int l15  = lane & 15, kgrp = lane >> 4;
  const int m0 = blockIdx.x * 128, n0 = blockIdx.y * 128;

  f32x4 acc[8][2];
  #pragma unroll
  for (int fi = 0; fi < 8; ++fi)
    #pragma unroll
    for (int fj = 0; fj < 2; ++fj) acc[fi][fj] = (f32x4){0.f, 0.f, 0.f, 0.f};

  const int arow = tid >> 1, ahalf = tid & 1;       // A: 2 thr/row, 16 k each
  const int bn = tid >> 1, bhalf = tid & 1;         // B: 2 thr/n-row, 16 k each

  for (int kb = 0; kb < K; kb += 32) {
    // stage A tile 128x32 -> hi/lo (in-kernel conversion)
    #pragma unroll
    for (int c = 0; c < 4; ++c) {
      float4 v = *(const float4*)&A[(size_t)(m0 + arow) * K + kb + ahalf * 16 + c * 4];
      int o = arow * 40 + ahalf * 16 + c * 4;
      ushort h0 = f2bf(v.x), h1 = f2bf(v.y), h2 = f2bf(v.z), h3 = f2bf(v.w);
      ushort4 H; H.x = h0; H.y = h1; H.z = h2; H.w = h3;
      ushort4 L; L.x = f2bf(v.x - bf2f(h0)); L.y = f2bf(v.y - bf2f(h1));
      L.z = f2bf(v.z - bf2f(h2)); L.w = f2bf(v.w - bf2f(h3));
      *(ushort4*)&Ahi[o] = H;
      *(ushort4*)&Alo[o] = L;
    }
    // stage B tile 128n x 32k: vectorized copies of pre-converted weights
    {
      const uint4* sH = (const uint4*)&BhiG[(size_t)(n0 + bn) * K + kb + bhalf * 16];
      const uint4* sL = (const uint4*)&BloG[(size_t)(n0 + bn) * K + kb + bhalf * 16];
      uint4* dH = (uint4*)&Bhi[bn * 40 + bhalf * 16];
      uint4* dL = (uint4*)&Blo[bn * 40 + bhalf * 16];
      dH[0] = sH[0]; dH[1] = sH[1];
      dL[0] = sL[0]; dL[1] = sL[1];
    }
    __syncthreads();

    bf16x8 aH[2], aL[2];
    #pragma unroll
    for (int fj = 0; fj < 2; ++fj) {
      const int mr = wave * 32 + fj * 16 + l15;
      aH[fj] = *(const bf16x8*)&Ahi[mr * 40 + kgrp * 8];
      aL[fj] = *(const bf16x8*)&Alo[mr * 40 + kgrp * 8];
    }
    #pragma unroll
    for (int fi = 0; fi < 8; ++fi) {
      const int nr = fi * 16 + l15;
      bf16x8 bH = *(const bf16x8*)&Bhi[nr * 40 + kgrp * 8];
      bf16x8 bL = *(const bf16x8*)&Blo[nr * 40 + kgrp * 8];
      #pragma unroll
      for (int fj = 0; fj < 2; ++fj) {
        acc[fi][fj] = __builtin_amdgcn_mfma_f32_16x16x32_bf16(aH[fj], bH, acc[fi][fj], 0, 0, 0);
        acc[fi][fj] = __builtin_amdgcn_mfma_f32_16x16x32_bf16(aH[fj], bL, acc[fi][fj], 0, 0, 0);
        acc[fi][fj] = __builtin_amdgcn_mfma_f32_16x16x32_bf16(aL[fj], bH, acc[fi][fj], 0, 0, 0);
      }
    }
    __syncthreads();
  }

  float bv[8];
  if (BIAS) {
    #pragma unroll
    for (int fi = 0; fi < 8; ++fi) bv[fi] = bias[n0 + fi * 16 + l15];
  }
  float rsv[2][4];
  if (RS) {
    #pragma unroll
    for (int fj = 0; fj < 2; ++fj)
      #pragma unroll
      for (int r = 0; r < 4; ++r)
        rsv[fj][r] = rowscale[m0 + wave * 32 + fj * 16 + kgrp * 4 + r];
  }
  #pragma unroll
  for (int fi = 0; fi < 8; ++fi) {
    const int n = n0 + fi * 16 + l15;
    #pragma unroll
    for (int fj = 0; fj < 2; ++fj) {
      #pragma unroll
      for (int r = 0; r < 4; ++r) {
        const int m = m0 + wave * 32 + fj * 16 + kgrp * 4 + r;
        float v = acc[fi][fj][r];
        if (BIAS) v += bv[fi];
        if (RS) v *= rsv[fj][r];
        if (RELU) v = fmaxf(v, 0.0f);
        C[(size_t)m * N + n] = v;
      }
    }
  }
}

// ===================== fused row-norms + bf16 cast (one pass over h) ==========
__global__ __launch_bounds__(256) void sq_split_kernel(
    const float* __restrict__ h, float* __restrict__ sq, ushort* __restrict__ hhi)
{
  const int w = threadIdx.x >> 6, l = threadIdx.x & 63;
  const int r = blockIdx.x * 4 + w;
  float4 v = *(const float4*)&h[(size_t)r * HD + l * 4];
  float s = v.x * v.x + v.y * v.y + v.z * v.z + v.w * v.w;
  #pragma unroll
  for (int o = 32; o; o >>= 1) s += __shfl_down(s, o);
  if (l == 0) sq[r] = s;
  ushort4 H; H.x = f2bf(v.x); H.y = f2bf(v.y); H.z = f2bf(v.z); H.w = f2bf(v.w);
  *(ushort4*)&hhi[(size_t)r * HD + l * 4] = H;
}

// sorted u32-key top-5 insert (k0<k1<...<k4); key embeds index -> unique; equal
// distance-bits -> lower index = lower key (matches JAX tie-break pre-rescore).
#define INS5K(v, k) do {                                                \
    if ((k) < v[4]) {                                                   \
      if ((k) < v[0])      { v[4]=v[3];v[3]=v[2];v[2]=v[1];v[1]=v[0];v[0]=(k); } \
      else if ((k) < v[1]) { v[4]=v[3];v[3]=v[2];v[2]=v[1];v[1]=(k); }  \
      else if ((k) < v[2]) { v[4]=v[3];v[3]=v[2];v[2]=(k); }            \
      else if ((k) < v[3]) { v[4]=v[3];v[3]=(k); }                      \
      else                 { v[4]=(k); }                                \
    }                                                                   \
  } while (0)

// ===================== MFMA pairwise-distance -> top-16 candidates per j-half ==========
// EXACT r18-measured kernel (367us, FETCH 35.7MB, WRITE 2KB).
__global__ __launch_bounds__(512, 2) void dist_topk_mfma(
    const ushort* __restrict__ hhi, const float* __restrict__ sq, int* __restrict__ cand)
{
  __shared__ char smem[67584];
  ushort*   iHi = (ushort*)smem;
  uint32_t* M   = (uint32_t*)smem;

  const int tid  = threadIdx.x;
  const int wave = tid >> 6, lane = tid & 63;
  const int l15  = lane & 15, kgrp = lane >> 4;
  const int rbase = blockIdx.x * 128;
  const int jbeg  = blockIdx.y * (NN / 2);

  {
    const int r = tid >> 2, q = tid & 3;
    const uint4* sH = (const uint4*)&hhi[(size_t)(rbase + r) * HD + q * 64];
    uint4* dH = (uint4*)&iHi[r * 264 + q * 64];
    #pragma unroll
    for (int c = 0; c < 8; ++c) dH[c] = sH[c];
  }
  __syncthreads();

  uint32_t keys[8][5];
  #pragma unroll
  for (int i = 0; i < 8; ++i)
    #pragma unroll
    for (int s = 0; s < 5; ++s) keys[i][s] = 0xFFFFFFFFu;

  for (int j0 = jbeg; j0 < jbeg + NN / 2; j0 += 256) {
    f32x4 acc[8][2];
    #pragma unroll
    for (int fi = 0; fi < 8; ++fi) {
      acc[fi][0] = (f32x4){0.f, 0.f, 0.f, 0.f};
      acc[fi][1] = (f32x4){0.f, 0.f, 0.f, 0.f};
    }

    #pragma unroll 2
    for (int kb = 0; kb < 8; ++kb) {
      bf16x8 a0 = *(const bf16x8*)&hhi[(size_t)(j0 + wave * 32 + l15) * HD + kb * 32 + kgrp * 8];
      bf16x8 a1 = *(const bf16x8*)&hhi[(size_t)(j0 + wave * 32 + 16 + l15) * HD + kb * 32 + kgrp * 8];
      #pragma unroll
      for (int fi = 0; fi < 8; ++fi) {
        bf16x8 b = *(const bf16x8*)&iHi[(fi * 16 + l15) * 264 + kb * 32 + kgrp * 8];
        acc[fi][0] = __builtin_amdgcn_mfma_f32_16x16x32_bf16(a0, b, acc[fi][0], 0, 0, 0);
        acc[fi][1] = __builtin_amdgcn_mfma_f32_16x16x32_bf16(a1, b, acc[fi][1], 0, 0, 0);
      }
    }

    float4 sqa = *(const float4*)&sq[j0 + wave * 32 + kgrp * 4];
    float4 sqb = *(const float4*)&sq[j0 + wave * 32 + 16 + kgrp * 4];
    float sqv[2][4] = { { sqa.x, sqa.y, sqa.z, sqa.w }, { sqb.x, sqb.y, sqb.z, sqb.w } };

    const bool selfchunk = ((rbase >> 8) == (j0 >> 8));

#define EPI_SLOT(fi, fj, r, CHECK)                                              \
    {                                                                           \
      const int jg = j0 + wave * 32 + (fj) * 16 + kgrp * 4 + (r);               \
      float d = fmaf(-2.0f, acc[fi][fj][r], sqv[fj][r]);                        \
      uint32_t u = __float_as_uint(d);                                          \
      u ^= (uint32_t)((int32_t)u >> 31) | 0x80000000u;                          \
      uint32_t key = (u & 0xFFFFC000u) | (uint32_t)jg;                          \
      if (!(CHECK) || jg != (rbase + (fi) * 16 + l15)) INS5K(keys[fi], key);    \
    }

    if (selfchunk) {
      #pragma unroll
      for (int fi = 0; fi < 8; ++fi)
        #pragma unroll
        for (int fj = 0; fj < 2; ++fj)
          #pragma unroll
          for (int r = 0; r < 4; ++r) EPI_SLOT(fi, fj, r, true)
    } else {
      #pragma unroll
      for (int fi = 0; fi < 8; ++fi)
        #pragma unroll
        for (int fj = 0; fj < 2; ++fj)
          #pragma unroll
          for (int r = 0; r < 4; ++r) EPI_SLOT(fi, fj, r, false)
    }
#undef EPI_SLOT
  }

  #pragma unroll
  for (int fi = 0; fi < 8; ++fi) {
    #pragma unroll
    for (int m = 16; m <= 32; m <<= 1) {
      uint32_t ok[5];
      #pragma unroll
      for (int s = 0; s < 5; ++s)
        ok[s] = (uint32_t)__shfl_xor((int)keys[fi][s], m);
      #pragma unroll
      for (int s = 0; s < 5; ++s) INS5K(keys[fi], ok[s]);
    }
  }

  __syncthreads();
  if (kgrp == 0) {
    #pragma unroll
    for (int fi = 0; fi < 8; ++fi) {
      const int row = fi * 16 + l15;
      #pragma unroll
      for (int s = 0; s < 5; ++s)
        M[row * 40 + wave * 5 + s] = keys[fi][s];
    }
  }
  __syncthreads();
  if (tid < 128) {
    const int irow = rbase + tid;
    int* co = &cand[(size_t)irow * NC2 + blockIdx.y * NCAND];
    #pragma unroll 1
    for (int s = 0; s < NCAND; ++s) {
      uint32_t best = 0xFFFFFFFFu; int bestt = 0;
      #pragma unroll 1
      for (int t = 0; t < 40; ++t) {
        uint32_t v = M[tid * 40 + t];
        if (v < best) { best = v; bestt = t; }
      }
      M[tid * 40 + bestt] = 0xFFFFFFFFu;
      co[s] = (int)(best & 0x3FFFu);
    }
  }
}

// ===================== exact fp32 rescore -> top-5 (+ fused in-degree count) ==========
__global__ __launch_bounds__(128) void rescore_kernel(
    const float* __restrict__ h, const float* __restrict__ sq,
    const int* __restrict__ cand, int* __restrict__ nbr, int* __restrict__ cnt)
{
  __shared__ float hi_s[HD];
  __shared__ float dv[NC2];
  __shared__ int   di[NC2];
  const int i = blockIdx.x;
  const int t = threadIdx.x;
  if (t < 64) *(float4*)&hi_s[t * 4] = *(const float4*)&h[(size_t)i * HD + t * 4];
  __syncthreads();
  const int c = t >> 2, q = t & 3;
  const int j = cand[(size_t)i * NC2 + c];
  float s = 0.f;
  const float4* hj  = (const float4*)&h[(size_t)j * HD + q * 64];
  const float4* hi4 = (const float4*)&hi_s[q * 64];
  #pragma unroll
  for (int u = 0; u < 16; ++u) {
    float4 a = hi4[u], b = hj[u];
    s = fmaf(a.x, b.x, s); s = fmaf(a.y, b.y, s);
    s = fmaf(a.z, b.z, s); s = fmaf(a.w, b.w, s);
  }
  s += __shfl_down(s, 1);
  s += __shfl_down(s, 2);
  if (q == 0) { dv[c] = fmaf(-2.0f, s, sq[j]); di[c] = j; }
  __syncthreads();
  if (t == 0) {
    #pragma unroll 1
    for (int sidx = 0; sidx < KNN; ++sidx) {
      float bestv = 3.0e38f; int bestid = 0x7fffffff; int bestc = 0;
      #pragma unroll 1
      for (int u = 0; u < NC2; ++u) {
        float v = dv[u]; int id = di[u];
        if (v < bestv || (v == bestv && id < bestid)) { bestv = v; bestid = id; bestc = u; }
      }
      dv[bestc] = 3.0e38f;
      nbr[i * KNN + sidx] = bestid;
      atomicAdd(&cnt[bestid], 1);
    }
  }
}

// ===================== CSR offsets + dinv (fused; deg = indeg + K + 1) ================
__global__ __launch_bounds__(256) void scan_kernel(
    const int* __restrict__ cnt, int* __restrict__ off, float* __restrict__ dinv)
{
  __shared__ int ps[256];
  const int t = threadIdx.x;
  int s = 0;
  for (int i = 0; i < 64; ++i) s += cnt[t * 64 + i];
  ps[t] = s;
  __syncthreads();
  if (t == 0) {
    int run = 0;
    for (int q = 0; q < 256; ++q) { int v = ps[q]; ps[q] = run; run += v; }
  }
  __syncthreads();
  int base = ps[t];
  for (int i = 0; i < 64; ++i) {
    int c = cnt[t * 64 + i];
    off[t * 64 + i] = base;
    dinv[t * 64 + i] = 1.0f / sqrtf((float)(c + KNN + 1));
    base += c;
  }
}

__global__ void fill_rev(const int* __restrict__ nbr, const int* __restrict__ off,
                         int* __restrict__ cur, int* __restrict__ rev)
{
  int e = blockIdx.x * 256 + threadIdx.x;
  if (e < NN * KNN) {
    int i = e / KNN;
    int c = nbr[e];
    int s = atomicAdd(&cur[c], 1);
    rev[off[c] + s] = i;
  }
}

// ===================== GCN aggregation (r18-measured 64-thread form) =================
__global__ __launch_bounds__(64) void aggregate(
    const float* __restrict__ g, const int* __restrict__ nbr,
    const int* __restrict__ rev, const int* __restrict__ off, const int* __restrict__ cnt,
    const float* __restrict__ dinv, const float* __restrict__ bias,
    float* __restrict__ out, int do_relu)
{
  const int c = blockIdx.x;
  const int l = threadIdx.x;
  const float4* g4 = (const float4*)g;
  float4 v = g4[(size_t)c * (HD / 4) + l];
  float ax = v.x, ay = v.y, az = v.z, aw = v.w;
  #pragma unroll
  for (int k = 0; k < KNN; ++k) {
    int r = nbr[c * KNN + k];
    float4 u = g4[(size_t)r * (HD / 4) + l];
    ax += u.x; ay += u.y; az += u.z; aw += u.w;
  }
  const int o0 = off[c], o1 = o0 + cnt[c];
  for (int j = o0; j < o1; ++j) {
    int r = rev[j];
    float4 u = g4[(size_t)r * (HD / 4) + l];
    ax += u.x; ay += u.y; az += u.z; aw += u.w;
  }
  const float dc = dinv[c];
  float4 b = ((const float4*)bias)[l];
  float rx = ax * dc + b.x, ry = ay * dc + b.y, rz = az * dc + b.z, rw = aw * dc + b.w;
  if (do_relu) {
    rx = fmaxf(rx, 0.0f); ry = fmaxf(ry, 0.0f);
    rz = fmaxf(rz, 0.0f); rw = fmaxf(rw, 0.0f);
  }
  float4 o; o.x = rx; o.y = ry; o.z = rz; o.w = rw;
  ((float4*)out)[(size_t)c * (HD / 4) + l] = o;
}

// ===================== mean-pool + classifier =====================
__global__ __launch_bounds__(256) void colsum_kernel(const float* __restrict__ a, float* __restrict__ colsum)
{
  const int f = threadIdx.x;
  const int r0 = blockIdx.x * 64;
  float s = 0.0f;
  for (int r = 0; r < 64; ++r) s += a[(size_t)(r0 + r) * HD + f];
  atomicAdd(&colsum[f], s);
}

__global__ __launch_bounds__(256) void final_kernel(
    const float* __restrict__ colsum, const float* __restrict__ Wc,
    const float* __restrict__ bc, float* __restrict__ out)
{
  __shared__ float s0[256], s1[256];
  const int f = threadIdx.x;
  float bag = colsum[f] * (1.0f / (float)NN);
  s0[f] = bag * Wc[f * 2 + 0];
  s1[f] = bag * Wc[f * 2 + 1];
  __syncthreads();
  for (int st = 128; st; st >>= 1) {
    if (f < st) { s0[f] += s0[f + st]; s1[f] += s1[f + st]; }
    __syncthreads();
  }
  if (f == 0) { out[0] = s0[0] + bc[0]; out[1] = s1[0] + bc[1]; }
}

// ===================== launch =====================
extern "C" void kernel_launch(void* const* d_in, const int* in_sizes, int n_in,
                              void* d_out, int out_size, void* d_ws, size_t ws_size,
                              hipStream_t stream)
{
  const float* x   = (const float*)d_in[0];
  const float* Wp  = (const float*)d_in[1];
  const float* bp  = (const float*)d_in[2];
  const float* Wg1 = (const float*)d_in[3];
  const float* bg1 = (const float*)d_in[4];
  const float* Wg2 = (const float*)d_in[5];
  const float* bg2 = (const float*)d_in[6];
  const float* Wc  = (const float*)d_in[7];
  const float* bc  = (const float*)d_in[8];
  float* out = (float*)d_out;

  // workspace plan (46.6 MB, down from 51.4):
  //  [0 .. 16.8M)  h  (steps 1-3b) -> h1 (7-8) -> agg2 (9-10)   [time-multiplexed]
  //  [16.8..33.6M) g  (GEMM outputs, steps 6-9)
  //  [33.6..42M)   hhi (bf16, steps 2-3a)
  //  then cand, nbr, cnt, off, cur, rev, sq, dinv, colsum, weight hi/lo
  float* ws    = (float*)d_ws;
  float* h     = ws;
  float* h1    = h;      // h dead after rescore
  float* agg2  = h;      // h1 dead after GEMM2
  float* g     = ws + (size_t)NN * HD;
  ushort* hhi  = (ushort*)(ws + 2 * (size_t)NN * HD);
  int* cand = (int*)(hhi + (size_t)NN * HD);        // N*NC2 ints
  int* nbr  = cand + (size_t)NN * NC2;              // N*KNN
  int* cnt  = nbr + NN * KNN;                       // N
  int* off  = cnt + NN;                             // N
  int* cur  = off + NN;                             // N
  int* rev  = cur + NN;                             // N*KNN
  float* sq     = (float*)(rev + NN * KNN);         // N
  float* dinv   = sq + NN;                          // N
  float* colsum = dinv + NN;                        // HD
  ushort* WpHi = (ushort*)(colsum + HD);            // IND*HD each
  ushort* WpLo = WpHi + (size_t)IND * HD;
  ushort* W1Hi = WpLo + (size_t)IND * HD;           // HD*HD each
  ushort* W1Lo = W1Hi + (size_t)HD * HD;
  ushort* W2Hi = W1Lo + (size_t)HD * HD;
  ushort* W2Lo = W2Hi + (size_t)HD * HD;

  // 0. one-time weight conversion (transposed bf16 hi/lo)
  convW_kernel<<<dim3(IND * HD / 256), dim3(256), 0, stream>>>(Wp, WpHi, WpLo, IND);
  convW_kernel<<<dim3(HD * HD / 256), dim3(256), 0, stream>>>(Wg1, W1Hi, W1Lo, HD);
  convW_kernel<<<dim3(HD * HD / 256), dim3(256), 0, stream>>>(Wg2, W2Hi, W2Lo, HD);

  // 1. h = relu(x @ W_proj + b_proj)
  gemm_mfma_pw<true, true, false><<<dim3(NN / 128, HD / 128), dim3(256), 0, stream>>>(
      x, WpHi, WpLo, bp, nullptr, h, NN, HD, IND);
  // 2. sq + bf16 cast (single pass over h)
  sq_split_kernel<<<dim3(NN / 4), dim3(256), 0, stream>>>(h, sq, hhi);
  // 3a. approx top-16 per j-half (r18-measured dist kernel)
  dist_topk_mfma<<<dim3(NN / 128, 2), dim3(512), 0, stream>>>(hhi, sq, cand);
  // 3b. exact fp32 rescore -> top-5, with fused in-degree counts
  hipMemsetAsync(cnt, 0, NN * sizeof(int), stream);
  rescore_kernel<<<dim3(NN), dim3(128), 0, stream>>>(h, sq, cand, nbr, cnt);
  // 4. CSR offsets + dinv (fused)
  scan_kernel<<<dim3(1), dim3(256), 0, stream>>>(cnt, off, dinv);
  // 5. reverse adjacency
  hipMemsetAsync(cur, 0, NN * sizeof(int), stream);
  fill_rev<<<dim3((NN * KNN) / 256), dim3(256), 0, stream>>>(nbr, off, cur, rev);
  // 6. g = (h @ W_g1) * dinv[row]
  gemm_mfma_pw<false, false, true><<<dim3(NN / 128, HD / 128), dim3(256), 0, stream>>>(
      h, W1Hi, W1Lo, nullptr, dinv, g, NN, HD, HD);
  // 7. h1 = relu(agg(g) + b_g1)   [h region reused: h dead after rescore]
  aggregate<<<dim3(NN), dim3(64), 0, stream>>>(g, nbr, rev, off, cnt, dinv, bg1, h1, 1);
  // 8. g = (h1 @ W_g2) * dinv[row]
  gemm_mfma_pw<false, false, true><<<dim3(NN / 128, HD / 128), dim3(256), 0, stream>>>(
      h1, W2Hi, W2Lo, nullptr, dinv, g, NN, HD, HD);
  // 9. agg2 = agg(g) + b_g2
  aggregate<<<dim3(NN), dim3(64), 0, stream>>>(g, nbr, rev, off, cnt, dinv, bg2, agg2, 0);
  // 10/11. mean-pool + classifier
  hipMemsetAsync(colsum, 0, HD * sizeof(float), stream);
  colsum_kernel<<<dim3(NN / 64), dim3(256), 0, stream>>>(agg2, colsum);
  final_kernel<<<dim3(1), dim3(256), 0, stream>>>(colsum, Wc, bc, out);
}

// Round 22
// 766.225 us; speedup vs baseline: 1.2655x; 1.1747x over previous
//
#include <hip/hip_runtime.h>
#include <cstdint>
#include <cstddef>

#define NN 16384
#define IND 1024
#define HD 256
#define KNN 5
#define NCAND 16   // per j-half
#define NC2 32     // total candidates per row (2 halves)

typedef __attribute__((ext_vector_type(4))) float f32x4;
typedef __attribute__((ext_vector_type(8))) short bf16x8;

// ===================== fp32 -> bf16 helpers =====================
__device__ __forceinline__ ushort f2bf(float f) {
  uint32_t u = __float_as_uint(f);
  uint32_t r = (u + 0x7fffu + ((u >> 16) & 1u)) >> 16;
  return (ushort)r;
}
__device__ __forceinline__ float bf2f(ushort s) {
  return __uint_as_float(((uint32_t)s) << 16);
}

// ===================== one-time weight conversion: [K][256] f32 -> [n][K] bf16 hi/lo ====
__global__ __launch_bounds__(256) void convW_kernel(
    const float* __restrict__ W, ushort* __restrict__ Whi, ushort* __restrict__ Wlo, int K)
{
  int idx = blockIdx.x * 256 + threadIdx.x;   // over K*256
  int k = idx >> 8, n = idx & 255;
  float v = W[idx];
  ushort h = f2bf(v);
  Whi[(size_t)n * K + k] = h;
  Wlo[(size_t)n * K + k] = f2bf(v - bf2f(h));
}

// ===================== MFMA GEMM, split-bf16 3-term, PRE-CONVERTED weights =============
template<bool RELU, bool BIAS, bool RS>
__global__ __launch_bounds__(256) void gemm_mfma_pw(
    const float* __restrict__ A, const ushort* __restrict__ BhiG,
    const ushort* __restrict__ BloG, const float* __restrict__ bias,
    const float* __restrict__ rowscale, float* __restrict__ C, int M, int N, int K)
{
  __shared__ ushort Ahi[128 * 40], Alo[128 * 40];   // [m][k], row 40 us (80B, padded)
  __shared__ ushort Bhi[128 * 40], Blo[128 * 40];   // [n][k]
  const int tid  = threadIdx.x;
  const int wave = tid >> 6, lane = tid & 63;
  const int l15  = lane & 15, kgrp = lane >> 4;
  const int m0 = blockIdx.x * 128, n0 = blockIdx.y * 128;

  f32x4 acc[8][2];
  #pragma unroll
  for (int fi = 0; fi < 8; ++fi)
    #pragma unroll
    for (int fj = 0; fj < 2; ++fj) acc[fi][fj] = (f32x4){0.f, 0.f, 0.f, 0.f};

  const int arow = tid >> 1, ahalf = tid & 1;       // A: 2 thr/row, 16 k each
  const int bn = tid >> 1, bhalf = tid & 1;         // B: 2 thr/n-row, 16 k each

  for (int kb = 0; kb < K; kb += 32) {
    #pragma unroll
    for (int c = 0; c < 4; ++c) {
      float4 v = *(const float4*)&A[(size_t)(m0 + arow) * K + kb + ahalf * 16 + c * 4];
      int o = arow * 40 + ahalf * 16 + c * 4;
      ushort h0 = f2bf(v.x), h1 = f2bf(v.y), h2 = f2bf(v.z), h3 = f2bf(v.w);
      ushort4 H; H.x = h0; H.y = h1; H.z = h2; H.w = h3;
      ushort4 L; L.x = f2bf(v.x - bf2f(h0)); L.y = f2bf(v.y - bf2f(h1));
      L.z = f2bf(v.z - bf2f(h2)); L.w = f2bf(v.w - bf2f(h3));
      *(ushort4*)&Ahi[o] = H;
      *(ushort4*)&Alo[o] = L;
    }
    {
      const uint4* sH = (const uint4*)&BhiG[(size_t)(n0 + bn) * K + kb + bhalf * 16];
      const uint4* sL = (const uint4*)&BloG[(size_t)(n0 + bn) * K + kb + bhalf * 16];
      uint4* dH = (uint4*)&Bhi[bn * 40 + bhalf * 16];
      uint4* dL = (uint4*)&Blo[bn * 40 + bhalf * 16];
      dH[0] = sH[0]; dH[1] = sH[1];
      dL[0] = sL[0]; dL[1] = sL[1];
    }
    __syncthreads();

    bf16x8 aH[2], aL[2];
    #pragma unroll
    for (int fj = 0; fj < 2; ++fj) {
      const int mr = wave * 32 + fj * 16 + l15;
      aH[fj] = *(const bf16x8*)&Ahi[mr * 40 + kgrp * 8];
      aL[fj] = *(const bf16x8*)&Alo[mr * 40 + kgrp * 8];
    }
    #pragma unroll
    for (int fi = 0; fi < 8; ++fi) {
      const int nr = fi * 16 + l15;
      bf16x8 bH = *(const bf16x8*)&Bhi[nr * 40 + kgrp * 8];
      bf16x8 bL = *(const bf16x8*)&Blo[nr * 40 + kgrp * 8];
      #pragma unroll
      for (int fj = 0; fj < 2; ++fj) {
        acc[fi][fj] = __builtin_amdgcn_mfma_f32_16x16x32_bf16(aH[fj], bH, acc[fi][fj], 0, 0, 0);
        acc[fi][fj] = __builtin_amdgcn_mfma_f32_16x16x32_bf16(aH[fj], bL, acc[fi][fj], 0, 0, 0);
        acc[fi][fj] = __builtin_amdgcn_mfma_f32_16x16x32_bf16(aL[fj], bH, acc[fi][fj], 0, 0, 0);
      }
    }
    __syncthreads();
  }

  float bv[8];
  if (BIAS) {
    #pragma unroll
    for (int fi = 0; fi < 8; ++fi) bv[fi] = bias[n0 + fi * 16 + l15];
  }
  float rsv[2][4];
  if (RS) {
    #pragma unroll
    for (int fj = 0; fj < 2; ++fj)
      #pragma unroll
      for (int r = 0; r < 4; ++r)
        rsv[fj][r] = rowscale[m0 + wave * 32 + fj * 16 + kgrp * 4 + r];
  }
  #pragma unroll
  for (int fi = 0; fi < 8; ++fi) {
    const int n = n0 + fi * 16 + l15;
    #pragma unroll
    for (int fj = 0; fj < 2; ++fj) {
      #pragma unroll
      for (int r = 0; r < 4; ++r) {
        const int m = m0 + wave * 32 + fj * 16 + kgrp * 4 + r;
        float v = acc[fi][fj][r];
        if (BIAS) v += bv[fi];
        if (RS) v *= rsv[fj][r];
        if (RELU) v = fmaxf(v, 0.0f);
        C[(size_t)m * N + n] = v;
      }
    }
  }
}

// ===================== fused row-norms + bf16 cast (one pass over h) ==========
__global__ __launch_bounds__(256) void sq_split_kernel(
    const float* __restrict__ h, float* __restrict__ sq, ushort* __restrict__ hhi)
{
  const int w = threadIdx.x >> 6, l = threadIdx.x & 63;
  const int r = blockIdx.x * 4 + w;
  float4 v = *(const float4*)&h[(size_t)r * HD + l * 4];
  float s = v.x * v.x + v.y * v.y + v.z * v.z + v.w * v.w;
  #pragma unroll
  for (int o = 32; o; o >>= 1) s += __shfl_down(s, o);
  if (l == 0) sq[r] = s;
  ushort4 H; H.x = f2bf(v.x); H.y = f2bf(v.y); H.z = f2bf(v.z); H.w = f2bf(v.w);
  *(ushort4*)&hhi[(size_t)r * HD + l * 4] = H;
}

// sorted u32-key top-5 insert (k0<k1<...<k4)
#define INS5K(v, k) do {                                                \
    if ((k) < v[4]) {                                                   \
      if ((k) < v[0])      { v[4]=v[3];v[3]=v[2];v[2]=v[1];v[1]=v[0];v[0]=(k); } \
      else if ((k) < v[1]) { v[4]=v[3];v[3]=v[2];v[2]=v[1];v[1]=(k); }  \
      else if ((k) < v[2]) { v[4]=v[3];v[3]=v[2];v[2]=(k); }            \
      else if ((k) < v[3]) { v[4]=v[3];v[3]=(k); }                      \
      else                 { v[4]=(k); }                                \
    }                                                                   \
  } while (0)

// ===================== MFMA pairwise-distance -> top-16 candidates per j-half ==========
// EXACT r18-measured kernel (367us, FETCH 35.7MB, WRITE 2KB).
__global__ __launch_bounds__(512, 2) void dist_topk_mfma(
    const ushort* __restrict__ hhi, const float* __restrict__ sq, int* __restrict__ cand)
{
  __shared__ char smem[67584];
  ushort*   iHi = (ushort*)smem;
  uint32_t* M   = (uint32_t*)smem;

  const int tid  = threadIdx.x;
  const int wave = tid >> 6, lane = tid & 63;
  const int l15  = lane & 15, kgrp = lane >> 4;
  const int rbase = blockIdx.x * 128;
  const int jbeg  = blockIdx.y * (NN / 2);

  {
    const int r = tid >> 2, q = tid & 3;
    const uint4* sH = (const uint4*)&hhi[(size_t)(rbase + r) * HD + q * 64];
    uint4* dH = (uint4*)&iHi[r * 264 + q * 64];
    #pragma unroll
    for (int c = 0; c < 8; ++c) dH[c] = sH[c];
  }
  __syncthreads();

  uint32_t keys[8][5];
  #pragma unroll
  for (int i = 0; i < 8; ++i)
    #pragma unroll
    for (int s = 0; s < 5; ++s) keys[i][s] = 0xFFFFFFFFu;

  for (int j0 = jbeg; j0 < jbeg + NN / 2; j0 += 256) {
    f32x4 acc[8][2];
    #pragma unroll
    for (int fi = 0; fi < 8; ++fi) {
      acc[fi][0] = (f32x4){0.f, 0.f, 0.f, 0.f};
      acc[fi][1] = (f32x4){0.f, 0.f, 0.f, 0.f};
    }

    #pragma unroll 2
    for (int kb = 0; kb < 8; ++kb) {
      bf16x8 a0 = *(const bf16x8*)&hhi[(size_t)(j0 + wave * 32 + l15) * HD + kb * 32 + kgrp * 8];
      bf16x8 a1 = *(const bf16x8*)&hhi[(size_t)(j0 + wave * 32 + 16 + l15) * HD + kb * 32 + kgrp * 8];
      #pragma unroll
      for (int fi = 0; fi < 8; ++fi) {
        bf16x8 b = *(const bf16x8*)&iHi[(fi * 16 + l15) * 264 + kb * 32 + kgrp * 8];
        acc[fi][0] = __builtin_amdgcn_mfma_f32_16x16x32_bf16(a0, b, acc[fi][0], 0, 0, 0);
        acc[fi][1] = __builtin_amdgcn_mfma_f32_16x16x32_bf16(a1, b, acc[fi][1], 0, 0, 0);
      }
    }

    float4 sqa = *(const float4*)&sq[j0 + wave * 32 + kgrp * 4];
    float4 sqb = *(const float4*)&sq[j0 + wave * 32 + 16 + kgrp * 4];
    float sqv[2][4] = { { sqa.x, sqa.y, sqa.z, sqa.w }, { sqb.x, sqb.y, sqb.z, sqb.w } };

    const bool selfchunk = ((rbase >> 8) == (j0 >> 8));

#define EPI_SLOT(fi, fj, r, CHECK)                                              \
    {                                                                           \
      const int jg = j0 + wave * 32 + (fj) * 16 + kgrp * 4 + (r);               \
      float d = fmaf(-2.0f, acc[fi][fj][r], sqv[fj][r]);                        \
      uint32_t u = __float_as_uint(d);                                          \
      u ^= (uint32_t)((int32_t)u >> 31) | 0x80000000u;                          \
      uint32_t key = (u & 0xFFFFC000u) | (uint32_t)jg;                          \
      if (!(CHECK) || jg != (rbase + (fi) * 16 + l15)) INS5K(keys[fi], key);    \
    }

    if (selfchunk) {
      #pragma unroll
      for (int fi = 0; fi < 8; ++fi)
        #pragma unroll
        for (int fj = 0; fj < 2; ++fj)
          #pragma unroll
          for (int r = 0; r < 4; ++r) EPI_SLOT(fi, fj, r, true)
    } else {
      #pragma unroll
      for (int fi = 0; fi < 8; ++fi)
        #pragma unroll
        for (int fj = 0; fj < 2; ++fj)
          #pragma unroll
          for (int r = 0; r < 4; ++r) EPI_SLOT(fi, fj, r, false)
    }
#undef EPI_SLOT
  }

  #pragma unroll
  for (int fi = 0; fi < 8; ++fi) {
    #pragma unroll
    for (int m = 16; m <= 32; m <<= 1) {
      uint32_t ok[5];
      #pragma unroll
      for (int s = 0; s < 5; ++s)
        ok[s] = (uint32_t)__shfl_xor((int)keys[fi][s], m);
      #pragma unroll
      for (int s = 0; s < 5; ++s) INS5K(keys[fi], ok[s]);
    }
  }

  __syncthreads();
  if (kgrp == 0) {
    #pragma unroll
    for (int fi = 0; fi < 8; ++fi) {
      const int row = fi * 16 + l15;
      #pragma unroll
      for (int s = 0; s < 5; ++s)
        M[row * 40 + wave * 5 + s] = keys[fi][s];
    }
  }
  __syncthreads();
  if (tid < 128) {
    const int irow = rbase + tid;
    int* co = &cand[(size_t)irow * NC2 + blockIdx.y * NCAND];
    #pragma unroll 1
    for (int s = 0; s < NCAND; ++s) {
      uint32_t best = 0xFFFFFFFFu; int bestt = 0;
      #pragma unroll 1
      for (int t = 0; t < 40; ++t) {
        uint32_t v = M[tid * 40 + t];
        if (v < best) { best = v; bestt = t; }
      }
      M[tid * 40 + bestt] = 0xFFFFFFFFu;
      co[s] = (int)(best & 0x3FFFu);
    }
  }
}

// ===================== exact fp32 rescore -> top-5 (+ fused in-degree count) ==========
__global__ __launch_bounds__(128) void rescore_kernel(
    const float* __restrict__ h, const float* __restrict__ sq,
    const int* __restrict__ cand, int* __restrict__ nbr, int* __restrict__ cnt)
{
  __shared__ float hi_s[HD];
  __shared__ float dv[NC2];
  __shared__ int   di[NC2];
  const int i = blockIdx.x;
  const int t = threadIdx.x;
  if (t < 64) *(float4*)&hi_s[t * 4] = *(const float4*)&h[(size_t)i * HD + t * 4];
  __syncthreads();
  const int c = t >> 2, q = t & 3;
  const int j = cand[(size_t)i * NC2 + c];
  float s = 0.f;
  const float4* hj  = (const float4*)&h[(size_t)j * HD + q * 64];
  const float4* hi4 = (const float4*)&hi_s[q * 64];
  #pragma unroll
  for (int u = 0; u < 16; ++u) {
    float4 a = hi4[u], b = hj[u];
    s = fmaf(a.x, b.x, s); s = fmaf(a.y, b.y, s);
    s = fmaf(a.z, b.z, s); s = fmaf(a.w, b.w, s);
  }
  s += __shfl_down(s, 1);
  s += __shfl_down(s, 2);
  if (q == 0) { dv[c] = fmaf(-2.0f, s, sq[j]); di[c] = j; }
  __syncthreads();
  if (t == 0) {
    #pragma unroll 1
    for (int sidx = 0; sidx < KNN; ++sidx) {
      float bestv = 3.0e38f; int bestid = 0x7fffffff; int bestc = 0;
      #pragma unroll 1
      for (int u = 0; u < NC2; ++u) {
        float v = dv[u]; int id = di[u];
        if (v < bestv || (v == bestv && id < bestid)) { bestv = v; bestid = id; bestc = u; }
      }
      dv[bestc] = 3.0e38f;
      nbr[i * KNN + sidx] = bestid;
      atomicAdd(&cnt[bestid], 1);
    }
  }
}

// ===================== CSR offsets + dinv + w-init (fused; deg = indeg + K + 1) ========
__global__ __launch_bounds__(256) void scan_kernel(
    const int* __restrict__ cnt, int* __restrict__ off,
    float* __restrict__ dinv, float* __restrict__ w)
{
  __shared__ int ps[256];
  const int t = threadIdx.x;
  int s = 0;
  for (int i = 0; i < 64; ++i) s += cnt[t * 64 + i];
  ps[t] = s;
  __syncthreads();
  if (t == 0) {
    int run = 0;
    for (int q = 0; q < 256; ++q) { int v = ps[q]; ps[q] = run; run += v; }
  }
  __syncthreads();
  int base = ps[t];
  for (int i = 0; i < 64; ++i) {
    int c = cnt[t * 64 + i];
    off[t * 64 + i] = base;
    float dv = 1.0f / sqrtf((float)(c + KNN + 1));
    dinv[t * 64 + i] = dv;
    w[t * 64 + i] = dv;                 // init w[r] = dinv[r] (self term)
    base += c;
  }
}

// ===================== w[r] += edge contributions (mean-pool pre-weights) =============
// bag = mean_c agg2[c] = (1/N) Σ_r w[r] g[r] + b_g2, where
// w[r] = dinv[r] + Σ_{c: r∈nbr(c)} dinv[c] + Σ_{c∈nbr(r)} dinv[c].
// One pass over edges: (i, j=nbr[i][k]) -> w[j] += dinv[i], w[i] += dinv[j].
__global__ void wsum_kernel(const int* __restrict__ nbr, const float* __restrict__ dinv,
                            float* __restrict__ w)
{
  int e = blockIdx.x * 256 + threadIdx.x;
  if (e < NN * KNN) {
    int i = e / KNN;
    int j = nbr[e];
    atomicAdd(&w[j], dinv[i]);
    atomicAdd(&w[i], dinv[j]);
  }
}

__global__ void fill_rev(const int* __restrict__ nbr, const int* __restrict__ off,
                         int* __restrict__ cur, int* __restrict__ rev)
{
  int e = blockIdx.x * 256 + threadIdx.x;
  if (e < NN * KNN) {
    int i = e / KNN;
    int c = nbr[e];
    int s = atomicAdd(&cur[c], 1);
    rev[off[c] + s] = i;
  }
}

// ===================== GCN aggregation (r18-measured 64-thread form) =================
__global__ __launch_bounds__(64) void aggregate(
    const float* __restrict__ g, const int* __restrict__ nbr,
    const int* __restrict__ rev, const int* __restrict__ off, const int* __restrict__ cnt,
    const float* __restrict__ dinv, const float* __restrict__ bias,
    float* __restrict__ out, int do_relu)
{
  const int c = blockIdx.x;
  const int l = threadIdx.x;
  const float4* g4 = (const float4*)g;
  float4 v = g4[(size_t)c * (HD / 4) + l];
  float ax = v.x, ay = v.y, az = v.z, aw = v.w;
  #pragma unroll
  for (int k = 0; k < KNN; ++k) {
    int r = nbr[c * KNN + k];
    float4 u = g4[(size_t)r * (HD / 4) + l];
    ax += u.x; ay += u.y; az += u.z; aw += u.w;
  }
  const int o0 = off[c], o1 = o0 + cnt[c];
  for (int j = o0; j < o1; ++j) {
    int r = rev[j];
    float4 u = g4[(size_t)r * (HD / 4) + l];
    ax += u.x; ay += u.y; az += u.z; aw += u.w;
  }
  const float dc = dinv[c];
  float4 b = ((const float4*)bias)[l];
  float rx = ax * dc + b.x, ry = ay * dc + b.y, rz = az * dc + b.z, rw = aw * dc + b.w;
  if (do_relu) {
    rx = fmaxf(rx, 0.0f); ry = fmaxf(ry, 0.0f);
    rz = fmaxf(rz, 0.0f); rw = fmaxf(rw, 0.0f);
  }
  float4 o; o.x = rx; o.y = ry; o.z = rz; o.w = rw;
  ((float4*)out)[(size_t)c * (HD / 4) + l] = o;
}

// ===================== weighted column-sum of h1: colsum[f] = Σ_r w[r]*dinv[r]*h1[r][f] ==
__global__ __launch_bounds__(256) void wcolsum_kernel(
    const float* __restrict__ a, const float* __restrict__ w,
    const float* __restrict__ dinv, float* __restrict__ colsum)
{
  const int f = threadIdx.x;
  const int r0 = blockIdx.x * 64;
  float s = 0.0f;
  for (int r = 0; r < 64; ++r)
    s = fmaf(w[r0 + r] * dinv[r0 + r], a[(size_t)(r0 + r) * HD + f], s);
  atomicAdd(&colsum[f], s);
}

// ===================== final: bag = colsum/N @ W_g2 + b_g2; out = bag @ W_cls + b_cls ==
__global__ __launch_bounds__(256) void final2_kernel(
    const float* __restrict__ colsum, const float* __restrict__ Wg2,
    const float* __restrict__ bg2, const float* __restrict__ Wc,
    const float* __restrict__ bc, float* __restrict__ out)
{
  __shared__ float s0[256], s1[256];
  const int n = threadIdx.x;
  float acc = 0.f;
  #pragma unroll 4
  for (int k = 0; k < HD; ++k) acc = fmaf(colsum[k], Wg2[k * HD + n], acc);
  float v = acc * (1.0f / (float)NN) + bg2[n];
  s0[n] = v * Wc[n * 2 + 0];
  s1[n] = v * Wc[n * 2 + 1];
  __syncthreads();
  for (int st = 128; st; st >>= 1) {
    if (n < st) { s0[n] += s0[n + st]; s1[n] += s1[n + st]; }
    __syncthreads();
  }
  if (n == 0) { out[0] = s0[0] + bc[0]; out[1] = s1[0] + bc[1]; }
}

// ===================== launch =====================
extern "C" void kernel_launch(void* const* d_in, const int* in_sizes, int n_in,
                              void* d_out, int out_size, void* d_ws, size_t ws_size,
                              hipStream_t stream)
{
  const float* x   = (const float*)d_in[0];
  const float* Wp  = (const float*)d_in[1];
  const float* bp  = (const float*)d_in[2];
  const float* Wg1 = (const float*)d_in[3];
  const float* bg1 = (const float*)d_in[4];
  const float* Wg2 = (const float*)d_in[5];
  const float* bg2 = (const float*)d_in[6];
  const float* Wc  = (const float*)d_in[7];
  const float* bc  = (const float*)d_in[8];
  float* out = (float*)d_out;

  float* ws    = (float*)d_ws;
  float* h     = ws;                                // steps 1-3b, then h1 (7+)
  float* h1    = h;                                 // h dead after rescore
  float* g     = ws + (size_t)NN * HD;
  ushort* hhi  = (ushort*)(ws + 2 * (size_t)NN * HD);
  int* cand = (int*)(hhi + (size_t)NN * HD);        // N*NC2 ints
  int* nbr  = cand + (size_t)NN * NC2;              // N*KNN
  int* cnt  = nbr + NN * KNN;                       // N
  int* off  = cnt + NN;                             // N
  int* cur  = off + NN;                             // N
  int* rev  = cur + NN;                             // N*KNN
  float* sq     = (float*)(rev + NN * KNN);         // N
  float* dinv   = sq + NN;                          // N
  float* wgt    = dinv + NN;                        // N (mean-pool weights)
  float* colsum = wgt + NN;                         // HD
  ushort* WpHi = (ushort*)(colsum + HD);            // IND*HD each
  ushort* WpLo = WpHi + (size_t)IND * HD;
  ushort* W1Hi = WpLo + (size_t)IND * HD;           // HD*HD each
  ushort* W1Lo = W1Hi + (size_t)HD * HD;

  // 0. one-time weight conversion (transposed bf16 hi/lo); Wg2 stays f32 (used once)
  convW_kernel<<<dim3(IND * HD / 256), dim3(256), 0, stream>>>(Wp, WpHi, WpLo, IND);
  convW_kernel<<<dim3(HD * HD / 256), dim3(256), 0, stream>>>(Wg1, W1Hi, W1Lo, HD);

  // 1. h = relu(x @ W_proj + b_proj)
  gemm_mfma_pw<true, true, false><<<dim3(NN / 128, HD / 128), dim3(256), 0, stream>>>(
      x, WpHi, WpLo, bp, nullptr, h, NN, HD, IND);
  // 2. sq + bf16 cast (single pass over h)
  sq_split_kernel<<<dim3(NN / 4), dim3(256), 0, stream>>>(h, sq, hhi);
  // 3a. approx top-16 per j-half (r18-measured dist kernel)
  dist_topk_mfma<<<dim3(NN / 128, 2), dim3(512), 0, stream>>>(hhi, sq, cand);
  // 3b. exact fp32 rescore -> top-5, with fused in-degree counts
  hipMemsetAsync(cnt, 0, NN * sizeof(int), stream);
  rescore_kernel<<<dim3(NN), dim3(128), 0, stream>>>(h, sq, cand, nbr, cnt);
  // 4. CSR offsets + dinv + w-init (fused)
  scan_kernel<<<dim3(1), dim3(256), 0, stream>>>(cnt, off, dinv, wgt);
  // 5a. mean-pool pre-weights (edge scatter)
  wsum_kernel<<<dim3((NN * KNN) / 256), dim3(256), 0, stream>>>(nbr, dinv, wgt);
  // 5b. reverse adjacency
  hipMemsetAsync(cur, 0, NN * sizeof(int), stream);
  fill_rev<<<dim3((NN * KNN) / 256), dim3(256), 0, stream>>>(nbr, off, cur, rev);
  // 6. g = (h @ W_g1) * dinv[row]
  gemm_mfma_pw<false, false, true><<<dim3(NN / 128, HD / 128), dim3(256), 0, stream>>>(
      h, W1Hi, W1Lo, nullptr, dinv, g, NN, HD, HD);
  // 7. h1 = relu(agg(g) + b_g1)   [h region reused: h dead after rescore]
  aggregate<<<dim3(NN), dim3(64), 0, stream>>>(g, nbr, rev, off, cnt, dinv, bg1, h1, 1);
  // 8. weighted colsum of h1 (replaces GEMM2 + aggregate2 + colsum via algebra:
  //    mean_c agg2[c] = (1/N)(Σ_r w[r]dinv[r] h1[r]) @ W_g2 + b_g2)
  hipMemsetAsync(colsum, 0, HD * sizeof(float), stream);
  wcolsum_kernel<<<dim3(NN / 64), dim3(256), 0, stream>>>(h1, wgt, dinv, colsum);
  // 9. final: bag @ W_g2 -> @ W_cls
  final2_kernel<<<dim3(1), dim3(256), 0, stream>>>(colsum, Wg2, bg2, Wc, bc, out);
}

// Round 23
// 703.521 us; speedup vs baseline: 1.3783x; 1.0891x over previous
//
#include <hip/hip_runtime.h>
#include <cstdint>
#include <cstddef>

#define NN 16384
#define IND 1024
#define HD 256
#define KNN 5
#define NCAND 8    // per j-half (halved from 16: rescore traffic /2; +3 rank margin kept)
#define NC2 16     // total candidates per row (2 halves)

typedef __attribute__((ext_vector_type(4))) float f32x4;
typedef __attribute__((ext_vector_type(8))) short bf16x8;

// ===================== fp32 -> bf16 helpers =====================
__device__ __forceinline__ ushort f2bf(float f) {
  uint32_t u = __float_as_uint(f);
  uint32_t r = (u + 0x7fffu + ((u >> 16) & 1u)) >> 16;
  return (ushort)r;
}
__device__ __forceinline__ float bf2f(ushort s) {
  return __uint_as_float(((uint32_t)s) << 16);
}

// ===================== one-time weight conversion: [K][256] f32 -> [n][K] bf16 hi/lo ====
__global__ __launch_bounds__(256) void convW_kernel(
    const float* __restrict__ W, ushort* __restrict__ Whi, ushort* __restrict__ Wlo, int K)
{
  int idx = blockIdx.x * 256 + threadIdx.x;   // over K*256
  int k = idx >> 8, n = idx & 255;
  float v = W[idx];
  ushort h = f2bf(v);
  Whi[(size_t)n * K + k] = h;
  Wlo[(size_t)n * K + k] = f2bf(v - bf2f(h));
}

// ===================== MFMA GEMM, split-bf16 3-term, PRE-CONVERTED weights =============
template<bool RELU, bool BIAS, bool RS>
__global__ __launch_bounds__(256) void gemm_mfma_pw(
    const float* __restrict__ A, const ushort* __restrict__ BhiG,
    const ushort* __restrict__ BloG, const float* __restrict__ bias,
    const float* __restrict__ rowscale, float* __restrict__ C, int M, int N, int K)
{
  __shared__ ushort Ahi[128 * 40], Alo[128 * 40];   // [m][k], row 40 us (80B, padded)
  __shared__ ushort Bhi[128 * 40], Blo[128 * 40];   // [n][k]
  const int tid  = threadIdx.x;
  const int wave = tid >> 6, lane = tid & 63;
  const int l15  = lane & 15, kgrp = lane >> 4;
  const int m0 = blockIdx.x * 128, n0 = blockIdx.y * 128;

  f32x4 acc[8][2];
  #pragma unroll
  for (int fi = 0; fi < 8; ++fi)
    #pragma unroll
    for (int fj = 0; fj < 2; ++fj) acc[fi][fj] = (f32x4){0.f, 0.f, 0.f, 0.f};

  const int arow = tid >> 1, ahalf = tid & 1;       // A: 2 thr/row, 16 k each
  const int bn = tid >> 1, bhalf = tid & 1;         // B: 2 thr/n-row, 16 k each

  for (int kb = 0; kb < K; kb += 32) {
    #pragma unroll
    for (int c = 0; c < 4; ++c) {
      float4 v = *(const float4*)&A[(size_t)(m0 + arow) * K + kb + ahalf * 16 + c * 4];
      int o = arow * 40 + ahalf * 16 + c * 4;
      ushort h0 = f2bf(v.x), h1 = f2bf(v.y), h2 = f2bf(v.z), h3 = f2bf(v.w);
      ushort4 H; H.x = h0; H.y = h1; H.z = h2; H.w = h3;
      ushort4 L; L.x = f2bf(v.x - bf2f(h0)); L.y = f2bf(v.y - bf2f(h1));
      L.z = f2bf(v.z - bf2f(h2)); L.w = f2bf(v.w - bf2f(h3));
      *(ushort4*)&Ahi[o] = H;
      *(ushort4*)&Alo[o] = L;
    }
    {
      const uint4* sH = (const uint4*)&BhiG[(size_t)(n0 + bn) * K + kb + bhalf * 16];
      const uint4* sL = (const uint4*)&BloG[(size_t)(n0 + bn) * K + kb + bhalf * 16];
      uint4* dH = (uint4*)&Bhi[bn * 40 + bhalf * 16];
      uint4* dL = (uint4*)&Blo[bn * 40 + bhalf * 16];
      dH[0] = sH[0]; dH[1] = sH[1];
      dL[0] = sL[0]; dL[1] = sL[1];
    }
    __syncthreads();

    bf16x8 aH[2], aL[2];
    #pragma unroll
    for (int fj = 0; fj < 2; ++fj) {
      const int mr = wave * 32 + fj * 16 + l15;
      aH[fj] = *(const bf16x8*)&Ahi[mr * 40 + kgrp * 8];
      aL[fj] = *(const bf16x8*)&Alo[mr * 40 + kgrp * 8];
    }
    #pragma unroll
    for (int fi = 0; fi < 8; ++fi) {
      const int nr = fi * 16 + l15;
      bf16x8 bH = *(const bf16x8*)&Bhi[nr * 40 + kgrp * 8];
      bf16x8 bL = *(const bf16x8*)&Blo[nr * 40 + kgrp * 8];
      #pragma unroll
      for (int fj = 0; fj < 2; ++fj) {
        acc[fi][fj] = __builtin_amdgcn_mfma_f32_16x16x32_bf16(aH[fj], bH, acc[fi][fj], 0, 0, 0);
        acc[fi][fj] = __builtin_amdgcn_mfma_f32_16x16x32_bf16(aH[fj], bL, acc[fi][fj], 0, 0, 0);
        acc[fi][fj] = __builtin_amdgcn_mfma_f32_16x16x32_bf16(aL[fj], bH, acc[fi][fj], 0, 0, 0);
      }
    }
    __syncthreads();
  }

  float bv[8];
  if (BIAS) {
    #pragma unroll
    for (int fi = 0; fi < 8; ++fi) bv[fi] = bias[n0 + fi * 16 + l15];
  }
  float rsv[2][4];
  if (RS) {
    #pragma unroll
    for (int fj = 0; fj < 2; ++fj)
      #pragma unroll
      for (int r = 0; r < 4; ++r)
        rsv[fj][r] = rowscale[m0 + wave * 32 + fj * 16 + kgrp * 4 + r];
  }
  #pragma unroll
  for (int fi = 0; fi < 8; ++fi) {
    const int n = n0 + fi * 16 + l15;
    #pragma unroll
    for (int fj = 0; fj < 2; ++fj) {
      #pragma unroll
      for (int r = 0; r < 4; ++r) {
        const int m = m0 + wave * 32 + fj * 16 + kgrp * 4 + r;
        float v = acc[fi][fj][r];
        if (BIAS) v += bv[fi];
        if (RS) v *= rsv[fj][r];
        if (RELU) v = fmaxf(v, 0.0f);
        C[(size_t)m * N + n] = v;
      }
    }
  }
}

// ===================== fused row-norms + bf16 cast (one pass over h) ==========
__global__ __launch_bounds__(256) void sq_split_kernel(
    const float* __restrict__ h, float* __restrict__ sq, ushort* __restrict__ hhi)
{
  const int w = threadIdx.x >> 6, l = threadIdx.x & 63;
  const int r = blockIdx.x * 4 + w;
  float4 v = *(const float4*)&h[(size_t)r * HD + l * 4];
  float s = v.x * v.x + v.y * v.y + v.z * v.z + v.w * v.w;
  #pragma unroll
  for (int o = 32; o; o >>= 1) s += __shfl_down(s, o);
  if (l == 0) sq[r] = s;
  ushort4 H; H.x = f2bf(v.x); H.y = f2bf(v.y); H.z = f2bf(v.z); H.w = f2bf(v.w);
  *(ushort4*)&hhi[(size_t)r * HD + l * 4] = H;
}

// sorted u32-key top-5 insert (k0<k1<...<k4)
#define INS5K(v, k) do {                                                \
    if ((k) < v[4]) {                                                   \
      if ((k) < v[0])      { v[4]=v[3];v[3]=v[2];v[2]=v[1];v[1]=v[0];v[0]=(k); } \
      else if ((k) < v[1]) { v[4]=v[3];v[3]=v[2];v[2]=v[1];v[1]=(k); }  \
      else if ((k) < v[2]) { v[4]=v[3];v[3]=v[2];v[2]=(k); }            \
      else if ((k) < v[3]) { v[4]=v[3];v[3]=(k); }                      \
      else                 { v[4]=(k); }                                \
    }                                                                   \
  } while (0)

// ===================== MFMA pairwise-distance -> top-8 candidates per j-half ==========
// r18-measured kernel (367us, FETCH 35.7MB, WRITE 2KB); only the extraction count
// changed (16 -> 8 per half).
__global__ __launch_bounds__(512, 2) void dist_topk_mfma(
    const ushort* __restrict__ hhi, const float* __restrict__ sq, int* __restrict__ cand)
{
  __shared__ char smem[67584];
  ushort*   iHi = (ushort*)smem;
  uint32_t* M   = (uint32_t*)smem;

  const int tid  = threadIdx.x;
  const int wave = tid >> 6, lane = tid & 63;
  const int l15  = lane & 15, kgrp = lane >> 4;
  const int rbase = blockIdx.x * 128;
  const int jbeg  = blockIdx.y * (NN / 2);

  {
    const int r = tid >> 2, q = tid & 3;
    const uint4* sH = (const uint4*)&hhi[(size_t)(rbase + r) * HD + q * 64];
    uint4* dH = (uint4*)&iHi[r * 264 + q * 64];
    #pragma unroll
    for (int c = 0; c < 8; ++c) dH[c] = sH[c];
  }
  __syncthreads();

  uint32_t keys[8][5];
  #pragma unroll
  for (int i = 0; i < 8; ++i)
    #pragma unroll
    for (int s = 0; s < 5; ++s) keys[i][s] = 0xFFFFFFFFu;

  for (int j0 = jbeg; j0 < jbeg + NN / 2; j0 += 256) {
    f32x4 acc[8][2];
    #pragma unroll
    for (int fi = 0; fi < 8; ++fi) {
      acc[fi][0] = (f32x4){0.f, 0.f, 0.f, 0.f};
      acc[fi][1] = (f32x4){0.f, 0.f, 0.f, 0.f};
    }

    #pragma unroll 2
    for (int kb = 0; kb < 8; ++kb) {
      bf16x8 a0 = *(const bf16x8*)&hhi[(size_t)(j0 + wave * 32 + l15) * HD + kb * 32 + kgrp * 8];
      bf16x8 a1 = *(const bf16x8*)&hhi[(size_t)(j0 + wave * 32 + 16 + l15) * HD + kb * 32 + kgrp * 8];
      #pragma unroll
      for (int fi = 0; fi < 8; ++fi) {
        bf16x8 b = *(const bf16x8*)&iHi[(fi * 16 + l15) * 264 + kb * 32 + kgrp * 8];
        acc[fi][0] = __builtin_amdgcn_mfma_f32_16x16x32_bf16(a0, b, acc[fi][0], 0, 0, 0);
        acc[fi][1] = __builtin_amdgcn_mfma_f32_16x16x32_bf16(a1, b, acc[fi][1], 0, 0, 0);
      }
    }

    float4 sqa = *(const float4*)&sq[j0 + wave * 32 + kgrp * 4];
    float4 sqb = *(const float4*)&sq[j0 + wave * 32 + 16 + kgrp * 4];
    float sqv[2][4] = { { sqa.x, sqa.y, sqa.z, sqa.w }, { sqb.x, sqb.y, sqb.z, sqb.w } };

    const bool selfchunk = ((rbase >> 8) == (j0 >> 8));

#define EPI_SLOT(fi, fj, r, CHECK)                                              \
    {                                                                           \
      const int jg = j0 + wave * 32 + (fj) * 16 + kgrp * 4 + (r);               \
      float d = fmaf(-2.0f, acc[fi][fj][r], sqv[fj][r]);                        \
      uint32_t u = __float_as_uint(d);                                          \
      u ^= (uint32_t)((int32_t)u >> 31) | 0x80000000u;                          \
      uint32_t key = (u & 0xFFFFC000u) | (uint32_t)jg;                          \
      if (!(CHECK) || jg != (rbase + (fi) * 16 + l15)) INS5K(keys[fi], key);    \
    }

    if (selfchunk) {
      #pragma unroll
      for (int fi = 0; fi < 8; ++fi)
        #pragma unroll
        for (int fj = 0; fj < 2; ++fj)
          #pragma unroll
          for (int r = 0; r < 4; ++r) EPI_SLOT(fi, fj, r, true)
    } else {
      #pragma unroll
      for (int fi = 0; fi < 8; ++fi)
        #pragma unroll
        for (int fj = 0; fj < 2; ++fj)
          #pragma unroll
          for (int r = 0; r < 4; ++r) EPI_SLOT(fi, fj, r, false)
    }
#undef EPI_SLOT
  }

  #pragma unroll
  for (int fi = 0; fi < 8; ++fi) {
    #pragma unroll
    for (int m = 16; m <= 32; m <<= 1) {
      uint32_t ok[5];
      #pragma unroll
      for (int s = 0; s < 5; ++s)
        ok[s] = (uint32_t)__shfl_xor((int)keys[fi][s], m);
      #pragma unroll
      for (int s = 0; s < 5; ++s) INS5K(keys[fi], ok[s]);
    }
  }

  __syncthreads();
  if (kgrp == 0) {
    #pragma unroll
    for (int fi = 0; fi < 8; ++fi) {
      const int row = fi * 16 + l15;
      #pragma unroll
      for (int s = 0; s < 5; ++s)
        M[row * 40 + wave * 5 + s] = keys[fi][s];
    }
  }
  __syncthreads();
  if (tid < 128) {
    const int irow = rbase + tid;
    int* co = &cand[(size_t)irow * NC2 + blockIdx.y * NCAND];
    #pragma unroll 1
    for (int s = 0; s < NCAND; ++s) {
      uint32_t best = 0xFFFFFFFFu; int bestt = 0;
      #pragma unroll 1
      for (int t = 0; t < 40; ++t) {
        uint32_t v = M[tid * 40 + t];
        if (v < best) { best = v; bestt = t; }
      }
      M[tid * 40 + bestt] = 0xFFFFFFFFu;
      co[s] = (int)(best & 0x3FFFu);
    }
  }
}

// ===================== exact fp32 rescore of 16 candidates -> top-5 (+ count) =========
// 128 threads per row: 8 lanes per candidate, 32 dims each.
__global__ __launch_bounds__(128) void rescore_kernel(
    const float* __restrict__ h, const float* __restrict__ sq,
    const int* __restrict__ cand, int* __restrict__ nbr, int* __restrict__ cnt)
{
  __shared__ float hi_s[HD];
  __shared__ float dv[NC2];
  __shared__ int   di[NC2];
  const int i = blockIdx.x;
  const int t = threadIdx.x;
  if (t < 64) *(float4*)&hi_s[t * 4] = *(const float4*)&h[(size_t)i * HD + t * 4];
  __syncthreads();
  const int c = t >> 3, q = t & 7;       // candidate c (0..15), eighth q (32 dims)
  const int j = cand[(size_t)i * NC2 + c];
  float s = 0.f;
  const float4* hj  = (const float4*)&h[(size_t)j * HD + q * 32];
  const float4* hi4 = (const float4*)&hi_s[q * 32];
  #pragma unroll
  for (int u = 0; u < 8; ++u) {
    float4 a = hi4[u], b = hj[u];
    s = fmaf(a.x, b.x, s); s = fmaf(a.y, b.y, s);
    s = fmaf(a.z, b.z, s); s = fmaf(a.w, b.w, s);
  }
  s += __shfl_down(s, 1);
  s += __shfl_down(s, 2);
  s += __shfl_down(s, 4);
  if (q == 0) { dv[c] = fmaf(-2.0f, s, sq[j]); di[c] = j; }
  __syncthreads();
  if (t == 0) {
    #pragma unroll 1
    for (int sidx = 0; sidx < KNN; ++sidx) {
      float bestv = 3.0e38f; int bestid = 0x7fffffff; int bestc = 0;
      #pragma unroll 1
      for (int u = 0; u < NC2; ++u) {
        float v = dv[u]; int id = di[u];
        if (v < bestv || (v == bestv && id < bestid)) { bestv = v; bestid = id; bestc = u; }
      }
      dv[bestc] = 3.0e38f;
      nbr[i * KNN + sidx] = bestid;
      atomicAdd(&cnt[bestid], 1);
    }
  }
}

// ===================== CSR offsets + dinv + w-init (fused; deg = indeg + K + 1) ========
__global__ __launch_bounds__(256) void scan_kernel(
    const int* __restrict__ cnt, int* __restrict__ off,
    float* __restrict__ dinv, float* __restrict__ w)
{
  __shared__ int ps[256];
  const int t = threadIdx.x;
  int s = 0;
  for (int i = 0; i < 64; ++i) s += cnt[t * 64 + i];
  ps[t] = s;
  __syncthreads();
  if (t == 0) {
    int run = 0;
    for (int q = 0; q < 256; ++q) { int v = ps[q]; ps[q] = run; run += v; }
  }
  __syncthreads();
  int base = ps[t];
  for (int i = 0; i < 64; ++i) {
    int c = cnt[t * 64 + i];
    off[t * 64 + i] = base;
    float dv = 1.0f / sqrtf((float)(c + KNN + 1));
    dinv[t * 64 + i] = dv;
    w[t * 64 + i] = dv;                 // init w[r] = dinv[r] (self term)
    base += c;
  }
}

// ===================== w[r] += edge contributions (mean-pool pre-weights) =============
__global__ void wsum_kernel(const int* __restrict__ nbr, const float* __restrict__ dinv,
                            float* __restrict__ w)
{
  int e = blockIdx.x * 256 + threadIdx.x;
  if (e < NN * KNN) {
    int i = e / KNN;
    int j = nbr[e];
    atomicAdd(&w[j], dinv[i]);
    atomicAdd(&w[i], dinv[j]);
  }
}

__global__ void fill_rev(const int* __restrict__ nbr, const int* __restrict__ off,
                         int* __restrict__ cur, int* __restrict__ rev)
{
  int e = blockIdx.x * 256 + threadIdx.x;
  if (e < NN * KNN) {
    int i = e / KNN;
    int c = nbr[e];
    int s = atomicAdd(&cur[c], 1);
    rev[off[c] + s] = i;
  }
}

// ===================== GCN aggregation (r18-measured 64-thread form) =================
__global__ __launch_bounds__(64) void aggregate(
    const float* __restrict__ g, const int* __restrict__ nbr,
    const int* __restrict__ rev, const int* __restrict__ off, const int* __restrict__ cnt,
    const float* __restrict__ dinv, const float* __restrict__ bias,
    float* __restrict__ out, int do_relu)
{
  const int c = blockIdx.x;
  const int l = threadIdx.x;
  const float4* g4 = (const float4*)g;
  float4 v = g4[(size_t)c * (HD / 4) + l];
  float ax = v.x, ay = v.y, az = v.z, aw = v.w;
  #pragma unroll
  for (int k = 0; k < KNN; ++k) {
    int r = nbr[c * KNN + k];
    float4 u = g4[(size_t)r * (HD / 4) + l];
    ax += u.x; ay += u.y; az += u.z; aw += u.w;
  }
  const int o0 = off[c], o1 = o0 + cnt[c];
  for (int j = o0; j < o1; ++j) {
    int r = rev[j];
    float4 u = g4[(size_t)r * (HD / 4) + l];
    ax += u.x; ay += u.y; az += u.z; aw += u.w;
  }
  const float dc = dinv[c];
  float4 b = ((const float4*)bias)[l];
  float rx = ax * dc + b.x, ry = ay * dc + b.y, rz = az * dc + b.z, rw = aw * dc + b.w;
  if (do_relu) {
    rx = fmaxf(rx, 0.0f); ry = fmaxf(ry, 0.0f);
    rz = fmaxf(rz, 0.0f); rw = fmaxf(rw, 0.0f);
  }
  float4 o; o.x = rx; o.y = ry; o.z = rz; o.w = rw;
  ((float4*)out)[(size_t)c * (HD / 4) + l] = o;
}

// ===================== weighted column-sum of h1: colsum[f] = Σ_r w[r]*dinv[r]*h1[r][f] ==
__global__ __launch_bounds__(256) void wcolsum_kernel(
    const float* __restrict__ a, const float* __restrict__ w,
    const float* __restrict__ dinv, float* __restrict__ colsum)
{
  const int f = threadIdx.x;
  const int r0 = blockIdx.x * 64;
  float s = 0.0f;
  for (int r = 0; r < 64; ++r)
    s = fmaf(w[r0 + r] * dinv[r0 + r], a[(size_t)(r0 + r) * HD + f], s);
  atomicAdd(&colsum[f], s);
}

// ===================== final: bag = colsum/N @ W_g2 + b_g2; out = bag @ W_cls + b_cls ==
__global__ __launch_bounds__(256) void final2_kernel(
    const float* __restrict__ colsum, const float* __restrict__ Wg2,
    const float* __restrict__ bg2, const float* __restrict__ Wc,
    const float* __restrict__ bc, float* __restrict__ out)
{
  __shared__ float s0[256], s1[256];
  const int n = threadIdx.x;
  float acc = 0.f;
  #pragma unroll 4
  for (int k = 0; k < HD; ++k) acc = fmaf(colsum[k], Wg2[k * HD + n], acc);
  float v = acc * (1.0f / (float)NN) + bg2[n];
  s0[n] = v * Wc[n * 2 + 0];
  s1[n] = v * Wc[n * 2 + 1];
  __syncthreads();
  for (int st = 128; st; st >>= 1) {
    if (n < st) { s0[n] += s0[n + st]; s1[n] += s1[n + st]; }
    __syncthreads();
  }
  if (n == 0) { out[0] = s0[0] + bc[0]; out[1] = s1[0] + bc[1]; }
}

// ===================== launch =====================
extern "C" void kernel_launch(void* const* d_in, const int* in_sizes, int n_in,
                              void* d_out, int out_size, void* d_ws, size_t ws_size,
                              hipStream_t stream)
{
  const float* x   = (const float*)d_in[0];
  const float* Wp  = (const float*)d_in[1];
  const float* bp  = (const float*)d_in[2];
  const float* Wg1 = (const float*)d_in[3];
  const float* bg1 = (const float*)d_in[4];
  const float* Wg2 = (const float*)d_in[5];
  const float* bg2 = (const float*)d_in[6];
  const float* Wc  = (const float*)d_in[7];
  const float* bc  = (const float*)d_in[8];
  float* out = (float*)d_out;

  float* ws    = (float*)d_ws;
  float* h     = ws;                                // steps 1-3b, then h1 (7+)
  float* h1    = h;                                 // h dead after rescore
  float* g     = ws + (size_t)NN * HD;
  ushort* hhi  = (ushort*)(ws + 2 * (size_t)NN * HD);
  int* cand = (int*)(hhi + (size_t)NN * HD);        // N*NC2 ints
  int* nbr  = cand + (size_t)NN * NC2;              // N*KNN
  int* cnt  = nbr + NN * KNN;                       // N
  int* off  = cnt + NN;                             // N
  int* cur  = off + NN;                             // N
  int* rev  = cur + NN;                             // N*KNN
  float* sq     = (float*)(rev + NN * KNN);         // N
  float* dinv   = sq + NN;                          // N
  float* wgt    = dinv + NN;                        // N (mean-pool weights)
  float* colsum = wgt + NN;                         // HD
  ushort* WpHi = (ushort*)(colsum + HD);            // IND*HD each
  ushort* WpLo = WpHi + (size_t)IND * HD;
  ushort* W1Hi = WpLo + (size_t)IND * HD;           // HD*HD each
  ushort* W1Lo = W1Hi + (size_t)HD * HD;

  // 0. one-time weight conversion (transposed bf16 hi/lo); Wg2 stays f32 (used once)
  convW_kernel<<<dim3(IND * HD / 256), dim3(256), 0, stream>>>(Wp, WpHi, WpLo, IND);
  convW_kernel<<<dim3(HD * HD / 256), dim3(256), 0, stream>>>(Wg1, W1Hi, W1Lo, HD);

  // 1. h = relu(x @ W_proj + b_proj)
  gemm_mfma_pw<true, true, false><<<dim3(NN / 128, HD / 128), dim3(256), 0, stream>>>(
      x, WpHi, WpLo, bp, nullptr, h, NN, HD, IND);
  // 2. sq + bf16 cast (single pass over h)
  sq_split_kernel<<<dim3(NN / 4), dim3(256), 0, stream>>>(h, sq, hhi);
  // 3a. approx top-8 per j-half (r18-measured dist kernel)
  dist_topk_mfma<<<dim3(NN / 128, 2), dim3(512), 0, stream>>>(hhi, sq, cand);
  // 3b. exact fp32 rescore of 16 candidates -> top-5, with fused in-degree counts
  hipMemsetAsync(cnt, 0, NN * sizeof(int), stream);
  rescore_kernel<<<dim3(NN), dim3(128), 0, stream>>>(h, sq, cand, nbr, cnt);
  // 4. CSR offsets + dinv + w-init (fused)
  scan_kernel<<<dim3(1), dim3(256), 0, stream>>>(cnt, off, dinv, wgt);
  // 5a. mean-pool pre-weights (edge scatter)
  wsum_kernel<<<dim3((NN * KNN) / 256), dim3(256), 0, stream>>>(nbr, dinv, wgt);
  // 5b. reverse adjacency
  hipMemsetAsync(cur, 0, NN * sizeof(int), stream);
  fill_rev<<<dim3((NN * KNN) / 256), dim3(256), 0, stream>>>(nbr, off, cur, rev);
  // 6. g = (h @ W_g1) * dinv[row]
  gemm_mfma_pw<false, false, true><<<dim3(NN / 128, HD / 128), dim3(256), 0, stream>>>(
      h, W1Hi, W1Lo, nullptr, dinv, g, NN, HD, HD);
  // 7. h1 = relu(agg(g) + b_g1)   [h region reused: h dead after rescore]
  aggregate<<<dim3(NN), dim3(64), 0, stream>>>(g, nbr, rev, off, cnt, dinv, bg1, h1, 1);
  // 8. weighted colsum of h1 (algebraic replacement of GEMM2+aggregate2+colsum)
  hipMemsetAsync(colsum, 0, HD * sizeof(float), stream);
  wcolsum_kernel<<<dim3(NN / 64), dim3(256), 0, stream>>>(h1, wgt, dinv, colsum);
  // 9. final: bag @ W_g2 -> @ W_cls
  final2_kernel<<<dim3(1), dim3(256), 0, stream>>>(colsum, Wg2, bg2, Wc, bc, out);
}